// Round 18
// baseline (366.308 us; speedup 1.0000x reference)
//
#include <hip/hip_runtime.h>
#include <cstddef>

#define EDIM 512
#define KDIM 768
#define NB 64
#define NV 196
#define NT 64
#define MROWS_V (NB * NV) /* 12544 */
#define MROWS_T (NB * NT) /* 4096  */

typedef __attribute__((ext_vector_type(8))) short bf16x8;
typedef __attribute__((ext_vector_type(4))) float f32x4;

static __device__ inline unsigned short f2bf(float f) {  // round-to-nearest-even
  unsigned u = __float_as_uint(f);
  unsigned r = (u + 0x7fff + ((u >> 16) & 1)) >> 16;
  return (unsigned short)r;
}
static __device__ inline float bf2f(short s) {
  return __uint_as_float(((unsigned)(unsigned short)s) << 16);
}
// seg swizzle: for row-tiles read at fixed li, spreads bank-starts
static __device__ __forceinline__ int swz4(int r) { return (r + (r >> 2)) & 3; }

// async global->LDS, 16B per lane; LDS dest = wave-uniform base + lane*16
static __device__ __forceinline__ void gload16(const void* g, void* l) {
  __builtin_amdgcn_global_load_lds(
      (const __attribute__((address_space(1))) void*)g,
      (__attribute__((address_space(3))) void*)l, 16, 0, 0);
}

// ------- merged prep: fp32->bf16 convert (v_tok,t_tok) + W transpose->bf16 -------
__global__ void k_prep(const float* __restrict__ va, short* __restrict__ vo, int na8,
                       const float* __restrict__ ta, short* __restrict__ to, int nb8,
                       const float* __restrict__ W0, const float* __restrict__ W1,
                       short* __restrict__ T0, short* __restrict__ T1) {
  __shared__ float tile[32][33];
  int blk = blockIdx.x;
  int tid = threadIdx.x;
  if (blk < 6240) {
    int i = blk * 256 + tid;
    const float* in; short* outp; int idx;
    if (i < na8) { in = va; outp = vo; idx = i; }
    else { idx = i - na8; if (idx >= nb8) return; in = ta; outp = to; }
    float4 a = *(const float4*)(in + (size_t)idx * 8);
    float4 b = *(const float4*)(in + (size_t)idx * 8 + 4);
    bf16x8 v;
    v[0] = (short)f2bf(a.x); v[1] = (short)f2bf(a.y);
    v[2] = (short)f2bf(a.z); v[3] = (short)f2bf(a.w);
    v[4] = (short)f2bf(b.x); v[5] = (short)f2bf(b.y);
    v[6] = (short)f2bf(b.z); v[7] = (short)f2bf(b.w);
    *(bf16x8*)(outp + (size_t)idx * 8) = v;
  } else {
    int z = blk - 6240;            // 0..767 = 24 x 16 x 2
    int bx = z % 24, by = (z / 24) % 16, bz = z / 384;
    const float* W = bz ? W1 : W0;
    short*       T = bz ? T1 : T0;
    int k0 = bx * 32, n0 = by * 32;
    int tx = tid & 31, ty = tid >> 5;
    for (int i = ty; i < 32; i += 8)
      tile[i][tx] = W[(size_t)(k0 + i) * EDIM + n0 + tx];
    __syncthreads();
    for (int i = ty; i < 32; i += 8)
      T[(size_t)(n0 + i) * KDIM + k0 + tx] = (short)f2bf(tile[tx][i]);
  }
}

// ---------- MFMA projection (merged v+t), 128x128 tile: 16 MFMA/wave/kc ----
__global__ __launch_bounds__(256, 4) void k_proj_mfma2(
    const short* __restrict__ vX, const short* __restrict__ tX,
    const short* __restrict__ WvT, const short* __restrict__ WtT,
    const float* __restrict__ vb, const float* __restrict__ tb,
    short* __restrict__ vout, short* __restrict__ tout) {
  __shared__ short As[2][128 * 32];
  __shared__ short Bs[2][128 * 32];
  int y = blockIdx.y;
  const short* Xbf; const short* WT; const float* bias; short* Mbf; int r0;
  if (y < 98) { Xbf = vX; WT = WvT; bias = vb; Mbf = vout; r0 = y * 128; }
  else        { Xbf = tX; WT = WtT; bias = tb; Mbf = tout; r0 = (y - 98) * 128; }
  int n0 = blockIdx.x * 128;
  int tid = threadIdx.x;
  int w = tid >> 6, lane = tid & 63, lg = lane >> 4, li = lane & 15;
  int fsw = (li + (li >> 2)) & 3;

  const short* aSrc[2];
  const short* bSrc[2];
#pragma unroll
  for (int uu = 0; uu < 2; ++uu) {
    int u = uu * 256 + w * 64 + lane;
    int row = u >> 2, seg = u & 3;
    int ss = seg ^ swz4(row);
    aSrc[uu] = Xbf + (size_t)(r0 + row) * KDIM + ss * 8;
    bSrc[uu] = WT + (size_t)(n0 + row) * KDIM + ss * 8;
  }

  auto stage = [&](int bb) {
    short* Ad = &As[bb][0];
    short* Bd = &Bs[bb][0];
#pragma unroll
    for (int uu = 0; uu < 2; ++uu) {
      gload16(aSrc[uu], Ad + (uu * 256 + w * 64) * 8);
      aSrc[uu] += 32;
      gload16(bSrc[uu], Bd + (uu * 256 + w * 64) * 8);
      bSrc[uu] += 32;
    }
  };

  f32x4 acc[2][8];
#pragma unroll
  for (int i = 0; i < 2; ++i)
#pragma unroll
    for (int j = 0; j < 8; ++j) acc[i][j] = (f32x4){0.f, 0.f, 0.f, 0.f};

  stage(0);   // 4 loads in flight
  int cur = 0;
  const int NKC = KDIM / 32;  // 24
  for (int kc = 0; kc < NKC; ++kc) {
    __builtin_amdgcn_s_barrier();
    if (kc < NKC - 1) {
      stage(cur ^ 1);
      asm volatile("s_waitcnt vmcnt(4)" ::: "memory");
    } else {
      asm volatile("s_waitcnt vmcnt(0)" ::: "memory");
    }
    __builtin_amdgcn_s_barrier();
    const short* Ab = &As[cur][0];
    const short* Bb = &Bs[cur][0];
    bf16x8 bfr[8];
#pragma unroll
    for (int j = 0; j < 8; ++j)
      bfr[j] = *(const bf16x8*)(Bb + (j * 16 + li) * 32 + (lg ^ fsw) * 8);
    __builtin_amdgcn_s_setprio(1);
#pragma unroll
    for (int i = 0; i < 2; ++i) {
      bf16x8 afr = *(const bf16x8*)(Ab + ((w * 2 + i) * 16 + li) * 32 + (lg ^ fsw) * 8);
#pragma unroll
      for (int j = 0; j < 8; ++j)
        acc[i][j] = __builtin_amdgcn_mfma_f32_16x16x32_bf16(afr, bfr[j], acc[i][j], 0, 0, 0);
    }
    __builtin_amdgcn_s_setprio(0);
    cur ^= 1;
  }
#pragma unroll
  for (int j = 0; j < 8; ++j) {
    int n = n0 + j * 16 + li;
    float bb = bias[n];
#pragma unroll
    for (int i = 0; i < 2; ++i)
#pragma unroll
      for (int reg = 0; reg < 4; ++reg)
        Mbf[(size_t)(r0 + (w * 2 + i) * 16 + lg * 4 + reg) * EDIM + n] =
            (short)f2bf(acc[i][j][reg] + bb);
  }
}

// ------- per-row (bf16 in place): fc scalar + l2 normalize; merged v+t -------
__global__ void k_normfc2(short* __restrict__ vM, short* __restrict__ tM,
                          const float* __restrict__ vfcw, const float* __restrict__ tfcw,
                          const float* __restrict__ vfcb, const float* __restrict__ tfcb,
                          float* __restrict__ vwout, float* __restrict__ twout) {
  int blk = blockIdx.x;
  short* Mbf; const float* fcw; const float* fcb; float* wout; int row;
  if (blk < 3136) { Mbf = vM; fcw = vfcw; fcb = vfcb; wout = vwout;
                    row = blk * 4 + (threadIdx.x >> 6); if (row >= 12544) return; }
  else            { Mbf = tM; fcw = tfcw; fcb = tfcb; wout = twout;
                    row = (blk - 3136) * 4 + (threadIdx.x >> 6); if (row >= 4096) return; }
  int lane = threadIdx.x & 63;
  short* p = Mbf + (size_t)row * EDIM + lane * 8;
  bf16x8 v = *(bf16x8*)p;
  float4 w0 = *(const float4*)(fcw + lane * 8);
  float4 w1 = *(const float4*)(fcw + lane * 8 + 4);
  float a[8];
#pragma unroll
  for (int j = 0; j < 8; ++j) a[j] = bf2f(v[j]);
  float dot = a[0] * w0.x + a[1] * w0.y + a[2] * w0.z + a[3] * w0.w +
              a[4] * w1.x + a[5] * w1.y + a[6] * w1.z + a[7] * w1.w;
  float ss = a[0] * a[0] + a[1] * a[1] + a[2] * a[2] + a[3] * a[3] +
             a[4] * a[4] + a[5] * a[5] + a[6] * a[6] + a[7] * a[7];
  for (int s = 1; s < 64; s <<= 1) {
    dot += __shfl_xor(dot, s);
    ss += __shfl_xor(ss, s);
  }
  float inv = 1.0f / fmaxf(sqrtf(ss), 1e-12f);
#pragma unroll
  for (int j = 0; j < 8; ++j) v[j] = (short)f2bf(a[j] * inv);
  *(bf16x8*)p = v;
  if (lane == 0) wout[row] = dot + fcb[0];
}

// ---------------- softmax: blocks 0..63 vw rows (196), 64..127 tw rows (64, masked) ----
__global__ void k_softmax(float* __restrict__ vwf, float* __restrict__ twf,
                          const int* __restrict__ tlen) {
  __shared__ float red[8];
  int tid = threadIdx.x;
  if (blockIdx.x < 64) {
    int b = blockIdx.x;
    float x = (tid < NV) ? vwf[b * NV + tid] : -1e30f;
    float m = x;
    for (int s = 1; s < 64; s <<= 1) m = fmaxf(m, __shfl_xor(m, s));
    if ((tid & 63) == 0) red[tid >> 6] = m;
    __syncthreads();
    m = fmaxf(fmaxf(red[0], red[1]), fmaxf(red[2], red[3]));
    float e = (tid < NV) ? expf(x - m) : 0.0f;
    float s = e;
    for (int st = 1; st < 64; st <<= 1) s += __shfl_xor(s, st);
    if ((tid & 63) == 0) red[4 + (tid >> 6)] = s;
    __syncthreads();
    s = red[4] + red[5] + red[6] + red[7];
    if (tid < NV) vwf[b * NV + tid] = e / s;
  } else {
    int b = blockIdx.x - 64;
    if (tid < 64) {
      int len = tlen[b];
      float x = twf[b * NT + tid];
      bool valid = tid < len;
      float xv = valid ? x : -1e30f;
      float m = xv;
      for (int s = 1; s < 64; s <<= 1) m = fmaxf(m, __shfl_xor(m, s));
      float e = valid ? expf(x - m) : 0.0f;
      float s = e;
      for (int st = 1; st < 64; st <<= 1) s += __shfl_xor(s, st);
      twf[b * NT + tid] = e / s;
    }
  }
}

// ---------------- MFMA sim kernel: one block (8 waves) per (b, q-pair) --------------
// A staged in LDS (per-wave rows); B (te) read DIRECT from global into registers,
// double-buffered across kc (in flight over both barriers). -45% LDS traffic.
__global__ __launch_bounds__(512, 4) void k_sim(
    const short* __restrict__ ve_bf, const short* __restrict__ te_bf,
    const float* __restrict__ vwf, const float* __restrict__ twf,
    float* __restrict__ out, int* __restrict__ gMT, int* __restrict__ gMV) {
  __shared__ short As[2][208 * 32];   // linear, 64B row stride
  __shared__ float colv[8][64];
  __shared__ int   coli[8][64];
  __shared__ float redp[8];
  int n = blockIdx.x;
  int xcd = n & 7, idx = n >> 3;
  int b = xcd * 8 + (idx & 7);     // b-fastest within XCD chunk (ve L2-resident)
  int qq = idx >> 3;               // 0..31
  int tid = threadIdx.x;
  int w = tid >> 6, lane = tid & 63, lg = lane >> 4, li = lane & 15;
  int qsel = w >> 2, wr = w & 3;
  int q = 2 * qq + qsel;
  const short* Abf = ve_bf + (size_t)b * NV * EDIM;
  int fsw = (li + (li >> 2)) & 3;
  int nt = wr ? 3 : 4;
  int tbase = wr ? (1 + wr * 3) : 0;  // wr0:0-3, wr1:4-6, wr2:7-9, wr3:10-12

  const short* aSrc[2];
#pragma unroll
  for (int uu = 0; uu < 2; ++uu) {
    int u = uu * 512 + w * 64 + lane;
    int row = u >> 2;
    if (row > NV - 1) row = NV - 1;
    int seg = u & 3;
    int ss = seg ^ swz4(row);
    aSrc[uu] = Abf + (size_t)row * EDIM + ss * 8;
  }
  // per-lane B pointers: row = q*64... = qq*128 + qsel*64 + j*16+li, col = lg*8
  const short* bP[4];
#pragma unroll
  for (int j = 0; j < 4; ++j)
    bP[j] = te_bf + ((size_t)(qq * 128 + qsel * 64 + j * 16 + li)) * EDIM + lg * 8;

  auto stageA = [&](int bb) {        // w0-4: 2 loads, w5-7: 1 load
    short* Ad = &As[bb][0];
#pragma unroll
    for (int uu = 0; uu < 2; ++uu) {
      int u0 = uu * 512 + w * 64;
      if (u0 < NV * 4) {
        gload16(aSrc[uu], Ad + u0 * 8);
        aSrc[uu] += 32;
      }
    }
  };
  auto loadB = [&](bf16x8 (&dst)[4]) {   // 4 global loads -> regs
#pragma unroll
    for (int j = 0; j < 4; ++j) {
      dst[j] = *(const bf16x8*)bP[j];
      bP[j] += 32;
    }
  };

  f32x4 acc[4][4];
#pragma unroll
  for (int i = 0; i < 4; ++i)
#pragma unroll
    for (int j = 0; j < 4; ++j) acc[i][j] = (f32x4){0.f, 0.f, 0.f, 0.f};

  bf16x8 bA[4], bB[4];
  stageA(0);
  loadB(bA);                 // kc0's B
  int cur = 0;

  auto iter = [&](int kc, bf16x8 (&bcur)[4], bf16x8 (&bnext)[4]) {
    __builtin_amdgcn_s_barrier();    // all waves done reading As[cur^1]
    if (kc < 15) {
      stageA(cur ^ 1);
      loadB(bnext);
      if (w <= 4) asm volatile("s_waitcnt vmcnt(6)" ::: "memory");
      else        asm volatile("s_waitcnt vmcnt(5)" ::: "memory");
    } else {
      asm volatile("s_waitcnt vmcnt(0)" ::: "memory");
    }
    __builtin_amdgcn_s_barrier();    // As[cur] fully landed (all waves)
    const short* Ab2 = &As[cur][0];
    __builtin_amdgcn_s_setprio(1);
#pragma unroll
    for (int i = 0; i < 4; ++i) {
      if (i < nt) {
        bf16x8 afr = *(const bf16x8*)(Ab2 + ((tbase + i) * 16 + li) * 32 + (lg ^ fsw) * 8);
#pragma unroll
        for (int j = 0; j < 4; ++j)
          acc[i][j] = __builtin_amdgcn_mfma_f32_16x16x32_bf16(afr, bcur[j], acc[i][j], 0, 0, 0);
      }
    }
    __builtin_amdgcn_s_setprio(0);
    cur ^= 1;
  };

#pragma unroll
  for (int kp = 0; kp < 8; ++kp) {
    iter(2 * kp, bA, bB);
    iter(2 * kp + 1, bB, bA);
  }

  bool diag = (b == q);    // per-wave uniform
  bool diagblk = (b >> 1) == qq;  // block-uniform
  float ip = 0.f;

  if (diagblk) {
    // ---- full argmax path (indices + tie-break); only 64/2048 blocks
#pragma unroll
    for (int i = 0; i < 4; ++i) {
      if (i < nt) {
#pragma unroll
        for (int reg = 0; reg < 4; ++reg) {
          int v = (tbase + i) * 16 + lg * 4 + reg;
          float m = acc[i][0][reg];
          int ti = li;
#pragma unroll
          for (int j = 1; j < 4; ++j) {
            float vv = acc[i][j][reg];
            int t = j * 16 + li;
            if (vv > m) { m = vv; ti = t; }   // t ascending -> first-index kept
          }
          for (int d = 1; d < 16; d <<= 1) {  // within li-group (same row)
            float om = __shfl_xor(m, d);
            int oi = __shfl_xor(ti, d);
            if (om > m || (om == m && oi < ti)) { m = om; ti = oi; }
          }
          if (li == 0 && v < NV) {
            ip += vwf[b * NV + v] * m;
            if (diag) gMT[b * NV + v] = b * NT + ti;
          }
        }
      }
    }
    float cm[4]; int cv[4];
#pragma unroll
    for (int j = 0; j < 4; ++j) { cm[j] = -3.0e38f; cv[j] = 0; }
#pragma unroll
    for (int i = 0; i < 4; ++i) {
      if (i < nt) {
#pragma unroll
        for (int reg = 0; reg < 4; ++reg) {
          int v = (tbase + i) * 16 + lg * 4 + reg;
          bool ok = v < NV;
#pragma unroll
          for (int j = 0; j < 4; ++j) {
            float s = ok ? acc[i][j][reg] : -3.0e38f;
            if (s > cm[j]) { cm[j] = s; cv[j] = v; }  // v ascending per lane
          }
        }
      }
    }
#pragma unroll
    for (int j = 0; j < 4; ++j) {
      for (int d = 16; d < 64; d <<= 1) {   // mixes lg groups (same col)
        float om = __shfl_xor(cm[j], d);
        int ov = __shfl_xor(cv[j], d);
        if (om > cm[j] || (om == cm[j] && ov < cv[j])) { cm[j] = om; cv[j] = ov; }
      }
      if (lg == 0) { colv[w][j * 16 + li] = cm[j]; coli[w][j * 16 + li] = cv[j]; }
    }
  } else {
    // ---- value-only path (fmax trees, no index juggling)
#pragma unroll
    for (int i = 0; i < 4; ++i) {
      if (i < nt) {
#pragma unroll
        for (int reg = 0; reg < 4; ++reg) {
          int v = (tbase + i) * 16 + lg * 4 + reg;
          float m = fmaxf(fmaxf(acc[i][0][reg], acc[i][1][reg]),
                          fmaxf(acc[i][2][reg], acc[i][3][reg]));
          for (int d = 1; d < 16; d <<= 1) m = fmaxf(m, __shfl_xor(m, d));
          if (li == 0 && v < NV) ip += vwf[b * NV + v] * m;
        }
      }
    }
    float cm[4];
#pragma unroll
    for (int j = 0; j < 4; ++j) cm[j] = -3.0e38f;
#pragma unroll
    for (int i = 0; i < 4; ++i) {
      if (i < nt) {
#pragma unroll
      for (int reg = 0; reg < 4; ++reg) {
          int v = (tbase + i) * 16 + lg * 4 + reg;
          bool ok = v < NV;
#pragma unroll
          for (int j = 0; j < 4; ++j)
            cm[j] = fmaxf(cm[j], ok ? acc[i][j][reg] : -3.0e38f);
        }
      }
    }
#pragma unroll
    for (int j = 0; j < 4; ++j) {
      for (int d = 16; d < 64; d <<= 1) cm[j] = fmaxf(cm[j], __shfl_xor(cm[j], d));
      if (lg == 0) colv[w][j * 16 + li] = cm[j];
    }
  }
  for (int d = 1; d < 64; d <<= 1) ip += __shfl_xor(ip, d);
  if (lane == 0) redp[w] = ip;
  __syncthreads();
  if (tid < 128) {   // tid>>6==0 -> q0 (colv 0-3), ==1 -> q1 (colv 4-7)
    int qs = tid >> 6, t = tid & 63;
    int qe = 2 * qq + qs;
    float m = colv[qs * 4][t];
    if (diagblk) {
      int bi = coli[qs * 4][t];
#pragma unroll
      for (int w2 = 1; w2 < 4; ++w2) {
        float om = colv[qs * 4 + w2][t];
        int ov = coli[qs * 4 + w2][t];
        if (om > m || (om == m && ov < bi)) { m = om; bi = ov; }
      }
      if (b == qe) gMV[b * NT + t] = b * NV + bi;
    } else {
#pragma unroll
      for (int w2 = 1; w2 < 4; ++w2) m = fmaxf(m, colv[qs * 4 + w2][t]);
    }
    float p = twf[qe * NT + t] * m;
    for (int d = 1; d < 64; d <<= 1) p += __shfl_xor(p, d);
    if ((tid & 63) == 0) out[4096 + b * 64 + qe] = p;
  }
  if (tid == 0) {
    out[b * 64 + 2 * qq]     = redp[0] + redp[1] + redp[2] + redp[3];
    out[b * 64 + 2 * qq + 1] = redp[4] + redp[5] + redp[6] + redp[7];
  }
}

// ------- transpose-materialize (K-chunk-tiled dst [K/32][512][32]) + fused stats ----
__global__ void k_materialize(const short* __restrict__ ve_bf, const short* __restrict__ te_bf,
                              const int* __restrict__ gMT, const int* __restrict__ gMV,
                              const float* __restrict__ vwf, const float* __restrict__ twf,
                              short* __restrict__ tTw, short* __restrict__ mvT,
                              short* __restrict__ vTw, short* __restrict__ mtT,
                              float* __restrict__ statPart) {
  int z = blockIdx.z;
  int at = blockIdx.x, ct = blockIdx.y;
  int K = (z == 2 || z == 3) ? MROWS_V : MROWS_T;
  if (at * 64 >= K) return;
  const short* src; const int* g = 0; short* dst;
  bool applyW;
  const float* wS = (z <= 1) ? twf : vwf;
  if (z == 0)      { src = te_bf; dst = tTw; applyW = true;  }
  else if (z == 1) { src = ve_bf; g = gMV; dst = mvT; applyW = false; }
  else if (z == 2) { src = ve_bf; dst = vTw; applyW = true;  }
  else             { src = te_bf; g = gMT; dst = mtT; applyW = false; }
  __shared__ float tile[64][67];
  __shared__ float wrow[64];
  int tid = threadIdx.x;
  for (int u = tid; u < 512; u += 256) {
    int a = u >> 3, cseg = (u & 7) << 3;
    int ga = at * 64 + a;
    int row = g ? g[ga] : ga;
    bf16x8 vv = *(const bf16x8*)(src + (size_t)row * EDIM + ct * 64 + cseg);
#pragma unroll
    for (int j = 0; j < 8; j++) tile[a][cseg + j] = bf2f(vv[j]);
    if ((u & 7) == 0) wrow[a] = wS[ga];
  }
  __syncthreads();
  for (int u = tid; u < 512; u += 256) {
    int c = u >> 3, aseg = (u & 7) << 3;
    bf16x8 ov;
#pragma unroll
    for (int j = 0; j < 8; j++) {
      float x = tile[aseg + j][c];
      if (applyW) x *= wrow[aseg + j];
      ov[j] = (short)f2bf(x);
    }
    int kchunk = at * 2 + (aseg >> 5);   // K-chunk-tiled: [K/32][512][32]
    *(bf16x8*)(dst + ((size_t)kchunk * 512 + ct * 64 + c) * 32 + (aseg & 31)) = ov;
  }
  // ---- fused stats partials: 4 threads per column, 16 a's each
  int cl = tid >> 2, part = tid & 3;
  float s = 0, ssq = 0, sw = 0;
  for (int a = part * 16; a < part * 16 + 16; ++a) {
    float x = tile[a][cl];
    s += x; ssq += x * x; sw += wrow[a] * x;
  }
  for (int d = 1; d < 4; d <<= 1) {   // 4 consecutive lanes share a column
    s += __shfl_xor(s, d); ssq += __shfl_xor(ssq, d); sw += __shfl_xor(sw, d);
  }
  if (part == 0) {
    int cbase = (z == 0) ? 0 : (z == 1) ? 64 : (z == 2) ? 128 : 324;
    size_t sidx = ((size_t)(cbase + at) * 512 + ct * 64 + cl) * 3;
    statPart[sidx] = s; statPart[sidx + 1] = ssq; statPart[sidx + 2] = sw;
  }
}

__global__ void k_statfin(const float* __restrict__ statPart, float* __restrict__ stats) {
  int m = blockIdx.x, c = threadIdx.x;
  int R = (m < 2) ? MROWS_T : MROWS_V;
  int nchunk = (m < 2) ? 64 : 196;
  int base = (m == 0) ? 0 : (m == 1) ? 64 : (m == 2) ? 128 : 324;
  float s = 0, ss = 0, sw = 0;
  for (int ch = 0; ch < nchunk; ch++) {
    size_t idx = ((size_t)(base + ch) * 512 + c) * 3;
    s += statPart[idx]; ss += statPart[idx + 1]; sw += statPart[idx + 2];
  }
  float mean = s / R;
  float var = (ss - s * mean) / (R - 1);  // ddof=1
  float rstd = 1.0f / sqrtf(var);
  stats[(m * 3 + 0) * 512 + c] = mean;
  stats[(m * 3 + 1) * 512 + c] = rstd;
  stats[(m * 3 + 2) * 512 + c] = sw;
}

// ------- MFMA weighted GEMM on K-chunk-tiled operands: 128x128 tile, 8 waves -------
__global__ __launch_bounds__(512, 2) void k_wgemm2(
    const short* __restrict__ tTw, const short* __restrict__ mvT,
    const short* __restrict__ vTw, const short* __restrict__ mtT,
    float* __restrict__ Spart) {
  __shared__ short As[2][128 * 32];
  __shared__ short Bs[2][128 * 32];
  int c0 = blockIdx.x * 128, d0 = blockIdx.y * 128;
  int z = blockIdx.z;                 // 0..15
  int which = z >> 3, slice = z & 7;
  const short* A = which ? vTw : tTw;
  const short* B = which ? mtT : mvT;
  int K = which ? MROWS_V : MROWS_T;
  int nch = (K >> 3) >> 5;            // 49 or 16 chunks of 32
  size_t a0c = (size_t)slice * nch;   // starting K-chunk
  int tid = threadIdx.x;
  int w = tid >> 6, lane = tid & 63, lg = lane >> 4, li = lane & 15;
  int fsw = (li + (li >> 2)) & 3;

  const short* aSrc; const short* bSrc;
  {
    int row = tid >> 2, seg = tid & 3;   // 512 units = 128 rows x 4 segs
    int ss = seg ^ swz4(row);
    aSrc = A + (a0c * 512 + (size_t)(c0 + row)) * 32 + ss * 8;
    bSrc = B + (a0c * 512 + (size_t)(d0 + row)) * 32 + ss * 8;
  }

  auto stage = [&](int bb) {           // 2 loads/wave
    gload16(aSrc, &As[bb][0] + (w * 64) * 8);
    aSrc += 512 * 32;
    gload16(bSrc, &Bs[bb][0] + (w * 64) * 8);
    bSrc += 512 * 32;
  };

  f32x4 acc[8];
#pragma unroll
  for (int j = 0; j < 8; ++j) acc[j] = (f32x4){0.f, 0.f, 0.f, 0.f};

  stage(0);
  int cur = 0;
  for (int ch = 0; ch < nch; ++ch) {
    __builtin_amdgcn_s_barrier();
    if (ch < nch - 1) {
      stage(cur ^ 1);
      asm volatile("s_waitcnt vmcnt(2)" ::: "memory");
    } else {
      asm volatile("s_waitcnt vmcnt(0)" ::: "memory");
    }
    __builtin_amdgcn_s_barrier();
    const short* Ab = &As[cur][0];
    const short* Bb = &Bs[cur][0];
    bf16x8 afr = *(const bf16x8*)(Ab + (w * 16 + li) * 32 + (lg ^ fsw) * 8);
    __builtin_amdgcn_s_setprio(1);
#pragma unroll
    for (int j = 0; j < 8; ++j) {
      bf16x8 bfr = *(const bf16x8*)(Bb + (j * 16 + li) * 32 + (lg ^ fsw) * 8);
      acc[j] = __builtin_amdgcn_mfma_f32_16x16x32_bf16(afr, bfr, acc[j], 0, 0, 0);
    }
    __builtin_amdgcn_s_setprio(0);
    cur ^= 1;
  }
  float* outp = Spart + (size_t)z * 512 * 512;
#pragma unroll
  for (int j = 0; j < 8; ++j) {
    int d = d0 + j * 16 + li;
#pragma unroll
    for (int reg = 0; reg < 4; ++reg)
      outp[(size_t)(c0 + w * 16 + lg * 4 + reg) * 512 + d] = acc[j][reg];
  }
}

// ---------------- assemble c = (c1+c2)/2 from closed form; loss partials ----------
__global__ void k_assemble(const float* __restrict__ Spart, const float* __restrict__ stats,
                           float* __restrict__ lossPart) {
  int c = blockIdx.x, tid = threadIdx.x;
  float muT = stats[0 * 512 + c], rsT = stats[1 * 512 + c], swT = stats[2 * 512 + c];
  float muV = stats[6 * 512 + c], rsV = stats[7 * 512 + c], swV = stats[8 * 512 + c];
  const float W = 64.0f, invB = 1.0f / 64.0f;
  float on = 0, off = 0;
  for (int d = tid; d < 512; d += 256) {
    float s1 = 0, s2 = 0;
    for (int sl = 0; sl < 8; sl++) {
      s1 += Spart[((size_t)sl * 512 + c) * 512 + d];
      s2 += Spart[((size_t)(8 + sl) * 512 + c) * 512 + d];
    }
    float muMV = stats[3 * 512 + d], rsMV = stats[4 * 512 + d], swMV = stats[5 * 512 + d];
    float muMT = stats[9 * 512 + d], rsMT = stats[10 * 512 + d], swMT = stats[11 * 512 + d];
    float c1 = (s1 - muT * swMV - muMV * swT + muT * muMV * W) * rsT * rsMV * invB;
    float c2 = (s2 - muV * swMT - muMT * swV + muV * muMT * W) * rsV * rsMT * invB;
    float cc = 0.5f * (c1 + c2);
    if (d == c) { float dd = cc - 1.0f; on += dd * dd; }
    else off += cc * cc;
  }
  __shared__ float r1[4], r2[4];
  for (int s = 1; s < 64; s <<= 1) { on += __shfl_xor(on, s); off += __shfl_xor(off, s); }
  if ((tid & 63) == 0) { r1[tid >> 6] = on; r2[tid >> 6] = off; }
  __syncthreads();
  if (tid == 0) {
    lossPart[c * 2] = r1[0] + r1[1] + r1[2] + r1[3];
    lossPart[c * 2 + 1] = r2[0] + r2[1] + r2[2] + r2[3];
  }
}

__global__ void k_loss(const float* __restrict__ lossPart, float* __restrict__ out) {
  int tid = threadIdx.x;
  float on = 0, off = 0;
  for (int i = tid; i < 512; i += 256) { on += lossPart[2 * i]; off += lossPart[2 * i + 1]; }
  __shared__ float r1[4], r2[4];
  for (int s = 1; s < 64; s <<= 1) { on += __shfl_xor(on, s); off += __shfl_xor(off, s); }
  if ((tid & 63) == 0) { r1[tid >> 6] = on; r2[tid >> 6] = off; }
  __syncthreads();
  if (tid == 0)
    out[8192] = 0.1f * ((r1[0] + r1[1] + r1[2] + r1[3]) +
                        0.06f * (r2[0] + r2[1] + r2[2] + r2[3]));
}

extern "C" void kernel_launch(void* const* d_in, const int* in_sizes, int n_in,
                              void* d_out, int out_size, void* d_ws, size_t ws_size,
                              hipStream_t stream) {
  (void)in_sizes; (void)n_in; (void)out_size; (void)ws_size;
  const float* v_tok  = (const float*)d_in[1];
  const float* t_tok  = (const float*)d_in[3];
  const float* Wv_tok = (const float*)d_in[8];
  const float* Wt_tok = (const float*)d_in[10];
  const float* bv_tok = (const float*)d_in[9];
  const float* bt_tok = (const float*)d_in[11];
  const float* wv_fc  = (const float*)d_in[12];
  const float* bv_fc  = (const float*)d_in[13];
  const float* wt_fc  = (const float*)d_in[14];
  const float* bt_fc  = (const float*)d_in[15];
  const int*   tlen   = (const int*)d_in[16];
  float* out = (float*)d_out;

  char* wsb = (char*)d_ws;
  short* v_tok_bf = (short*)wsb;                       // 9,633,792 sh
  short* t_tok_bf = v_tok_bf + (size_t)9633792;        // 3,145,728 sh
  short* WvT      = t_tok_bf + (size_t)3145728;        //   393,216 sh
  short* WtT      = WvT + (size_t)393216;              //   393,216 sh
  short* tTw = (short*)wsb;                            // 512*4096 (alias, phase2)
  short* mvT = tTw + (size_t)2097152;                  // 512*4096
  short* vTw = mvT + (size_t)2097152;                  // 512*12544
  short* ve_bf = (short*)(wsb + 27131904);             // 6,422,528 sh
  short* te_bf = ve_bf + (size_t)6422528;              // 2,097,152 sh
  float* Spart = (float*)(wsb + 27131904);             // 16*512*512 f (alias, phase-b)
  short* mtT = (short*)(wsb + 44171264);               // 512*12544
  float* vwf = (float*)(wsb + 57016320);               // 12544
  float* twf = vwf + 12544;                            // 4096
  int* gMT = (int*)(twf + 4096);                       // 12544
  int* gMV = gMT + 12544;                              // 4096
  float* statPart = (float*)(gMV + 4096);              // 520*512*3 f (3.2 MB)
  float* stats = statPart + (size_t)520 * 512 * 3;     // 12*512
  float* lossPart = stats + 6144;                      // 1024

  k_prep<<<7008, 256, 0, stream>>>(v_tok, v_tok_bf, 1204224, t_tok, t_tok_bf, 393216,
                                   Wv_tok, Wt_tok, WvT, WtT);
  k_proj_mfma2<<<dim3(4, 130), 256, 0, stream>>>(v_tok_bf, t_tok_bf, WvT, WtT,
                                                 bv_tok, bt_tok, ve_bf, te_bf);
  k_normfc2<<<4160, 256, 0, stream>>>(ve_bf, te_bf, wv_fc, wt_fc, bv_fc, bt_fc, vwf, twf);
  k_softmax<<<128, 256, 0, stream>>>(vwf, twf, tlen);
  k_sim<<<2048, 512, 0, stream>>>(ve_bf, te_bf, vwf, twf, out, gMT, gMV);
  k_materialize<<<dim3(196, 8, 4), 256, 0, stream>>>(ve_bf, te_bf, gMT, gMV, vwf, twf,
                                                     tTw, mvT, vTw, mtT, statPart);
  k_statfin<<<4, 512, 0, stream>>>(statPart, stats);
  k_wgemm2<<<dim3(4, 4, 16), 512, 0, stream>>>(tTw, mvT, vTw, mtT, Spart);
  k_assemble<<<512, 256, 0, stream>>>(Spart, stats, lossPart);
  k_loss<<<1, 256, 0, stream>>>(lossPart, out);
}

// Round 19
// 247.139 us; speedup vs baseline: 1.4822x; 1.4822x over previous
//
#include <hip/hip_runtime.h>
#include <cstddef>

#define EDIM 512
#define KDIM 768
#define NB 64
#define NV 196
#define NT 64
#define MROWS_V (NB * NV) /* 12544 */
#define MROWS_T (NB * NT) /* 4096  */

typedef __attribute__((ext_vector_type(8))) short bf16x8;
typedef __attribute__((ext_vector_type(4))) float f32x4;

static __device__ inline unsigned short f2bf(float f) {  // round-to-nearest-even
  unsigned u = __float_as_uint(f);
  unsigned r = (u + 0x7fff + ((u >> 16) & 1)) >> 16;
  return (unsigned short)r;
}
static __device__ inline float bf2f(short s) {
  return __uint_as_float(((unsigned)(unsigned short)s) << 16);
}
// seg swizzle: for row-tiles read at fixed li, spreads bank-starts
static __device__ __forceinline__ int swz4(int r) { return (r + (r >> 2)) & 3; }

// async global->LDS, 16B per lane; LDS dest = wave-uniform base + lane*16
static __device__ __forceinline__ void gload16(const void* g, void* l) {
  __builtin_amdgcn_global_load_lds(
      (const __attribute__((address_space(1))) void*)g,
      (__attribute__((address_space(3))) void*)l, 16, 0, 0);
}

// ------- merged prep: fp32->bf16 convert (v_tok,t_tok) + W transpose->bf16 -------
__global__ void k_prep(const float* __restrict__ va, short* __restrict__ vo, int na8,
                       const float* __restrict__ ta, short* __restrict__ to, int nb8,
                       const float* __restrict__ W0, const float* __restrict__ W1,
                       short* __restrict__ T0, short* __restrict__ T1) {
  __shared__ float tile[32][33];
  int blk = blockIdx.x;
  int tid = threadIdx.x;
  if (blk < 6240) {
    int i = blk * 256 + tid;
    const float* in; short* outp; int idx;
    if (i < na8) { in = va; outp = vo; idx = i; }
    else { idx = i - na8; if (idx >= nb8) return; in = ta; outp = to; }
    float4 a = *(const float4*)(in + (size_t)idx * 8);
    float4 b = *(const float4*)(in + (size_t)idx * 8 + 4);
    bf16x8 v;
    v[0] = (short)f2bf(a.x); v[1] = (short)f2bf(a.y);
    v[2] = (short)f2bf(a.z); v[3] = (short)f2bf(a.w);
    v[4] = (short)f2bf(b.x); v[5] = (short)f2bf(b.y);
    v[6] = (short)f2bf(b.z); v[7] = (short)f2bf(b.w);
    *(bf16x8*)(outp + (size_t)idx * 8) = v;
  } else {
    int z = blk - 6240;            // 0..767 = 24 x 16 x 2
    int bx = z % 24, by = (z / 24) % 16, bz = z / 384;
    const float* W = bz ? W1 : W0;
    short*       T = bz ? T1 : T0;
    int k0 = bx * 32, n0 = by * 32;
    int tx = tid & 31, ty = tid >> 5;
    for (int i = ty; i < 32; i += 8)
      tile[i][tx] = W[(size_t)(k0 + i) * EDIM + n0 + tx];
    __syncthreads();
    for (int i = ty; i < 32; i += 8)
      T[(size_t)(n0 + i) * KDIM + k0 + tx] = (short)f2bf(tile[tx][i]);
  }
}

// ---------- MFMA projection (merged v+t), 128x128 tile: 16 MFMA/wave/kc ----
__global__ __launch_bounds__(256, 4) void k_proj_mfma2(
    const short* __restrict__ vX, const short* __restrict__ tX,
    const short* __restrict__ WvT, const short* __restrict__ WtT,
    const float* __restrict__ vb, const float* __restrict__ tb,
    short* __restrict__ vout, short* __restrict__ tout) {
  __shared__ short As[2][128 * 32];
  __shared__ short Bs[2][128 * 32];
  int y = blockIdx.y;
  const short* Xbf; const short* WT; const float* bias; short* Mbf; int r0;
  if (y < 98) { Xbf = vX; WT = WvT; bias = vb; Mbf = vout; r0 = y * 128; }
  else        { Xbf = tX; WT = WtT; bias = tb; Mbf = tout; r0 = (y - 98) * 128; }
  int n0 = blockIdx.x * 128;
  int tid = threadIdx.x;
  int w = tid >> 6, lane = tid & 63, lg = lane >> 4, li = lane & 15;
  int fsw = (li + (li >> 2)) & 3;

  const short* aSrc[2];
  const short* bSrc[2];
#pragma unroll
  for (int uu = 0; uu < 2; ++uu) {
    int u = uu * 256 + w * 64 + lane;
    int row = u >> 2, seg = u & 3;
    int ss = seg ^ swz4(row);
    aSrc[uu] = Xbf + (size_t)(r0 + row) * KDIM + ss * 8;
    bSrc[uu] = WT + (size_t)(n0 + row) * KDIM + ss * 8;
  }

  auto stage = [&](int bb) {
    short* Ad = &As[bb][0];
    short* Bd = &Bs[bb][0];
#pragma unroll
    for (int uu = 0; uu < 2; ++uu) {
      gload16(aSrc[uu], Ad + (uu * 256 + w * 64) * 8);
      aSrc[uu] += 32;
      gload16(bSrc[uu], Bd + (uu * 256 + w * 64) * 8);
      bSrc[uu] += 32;
    }
  };

  f32x4 acc[2][8];
#pragma unroll
  for (int i = 0; i < 2; ++i)
#pragma unroll
    for (int j = 0; j < 8; ++j) acc[i][j] = (f32x4){0.f, 0.f, 0.f, 0.f};

  stage(0);   // 4 loads in flight
  int cur = 0;
  const int NKC = KDIM / 32;  // 24
  for (int kc = 0; kc < NKC; ++kc) {
    __builtin_amdgcn_s_barrier();
    if (kc < NKC - 1) {
      stage(cur ^ 1);
      asm volatile("s_waitcnt vmcnt(4)" ::: "memory");
    } else {
      asm volatile("s_waitcnt vmcnt(0)" ::: "memory");
    }
    __builtin_amdgcn_s_barrier();
    const short* Ab = &As[cur][0];
    const short* Bb = &Bs[cur][0];
    bf16x8 bfr[8];
#pragma unroll
    for (int j = 0; j < 8; ++j)
      bfr[j] = *(const bf16x8*)(Bb + (j * 16 + li) * 32 + (lg ^ fsw) * 8);
    __builtin_amdgcn_s_setprio(1);
#pragma unroll
    for (int i = 0; i < 2; ++i) {
      bf16x8 afr = *(const bf16x8*)(Ab + ((w * 2 + i) * 16 + li) * 32 + (lg ^ fsw) * 8);
#pragma unroll
      for (int j = 0; j < 8; ++j)
        acc[i][j] = __builtin_amdgcn_mfma_f32_16x16x32_bf16(afr, bfr[j], acc[i][j], 0, 0, 0);
    }
    __builtin_amdgcn_s_setprio(0);
    cur ^= 1;
  }
#pragma unroll
  for (int j = 0; j < 8; ++j) {
    int n = n0 + j * 16 + li;
    float bb = bias[n];
#pragma unroll
    for (int i = 0; i < 2; ++i)
#pragma unroll
      for (int reg = 0; reg < 4; ++reg)
        Mbf[(size_t)(r0 + (w * 2 + i) * 16 + lg * 4 + reg) * EDIM + n] =
            (short)f2bf(acc[i][j][reg] + bb);
  }
}

// ------- per-row (bf16 in place): fc scalar + l2 normalize; merged v+t -------
__global__ void k_normfc2(short* __restrict__ vM, short* __restrict__ tM,
                          const float* __restrict__ vfcw, const float* __restrict__ tfcw,
                          const float* __restrict__ vfcb, const float* __restrict__ tfcb,
                          float* __restrict__ vwout, float* __restrict__ twout) {
  int blk = blockIdx.x;
  short* Mbf; const float* fcw; const float* fcb; float* wout; int row;
  if (blk < 3136) { Mbf = vM; fcw = vfcw; fcb = vfcb; wout = vwout;
                    row = blk * 4 + (threadIdx.x >> 6); if (row >= 12544) return; }
  else            { Mbf = tM; fcw = tfcw; fcb = tfcb; wout = twout;
                    row = (blk - 3136) * 4 + (threadIdx.x >> 6); if (row >= 4096) return; }
  int lane = threadIdx.x & 63;
  short* p = Mbf + (size_t)row * EDIM + lane * 8;
  bf16x8 v = *(bf16x8*)p;
  float4 w0 = *(const float4*)(fcw + lane * 8);
  float4 w1 = *(const float4*)(fcw + lane * 8 + 4);
  float a[8];
#pragma unroll
  for (int j = 0; j < 8; ++j) a[j] = bf2f(v[j]);
  float dot = a[0] * w0.x + a[1] * w0.y + a[2] * w0.z + a[3] * w0.w +
              a[4] * w1.x + a[5] * w1.y + a[6] * w1.z + a[7] * w1.w;
  float ss = a[0] * a[0] + a[1] * a[1] + a[2] * a[2] + a[3] * a[3] +
             a[4] * a[4] + a[5] * a[5] + a[6] * a[6] + a[7] * a[7];
  for (int s = 1; s < 64; s <<= 1) {
    dot += __shfl_xor(dot, s);
    ss += __shfl_xor(ss, s);
  }
  float inv = 1.0f / fmaxf(sqrtf(ss), 1e-12f);
#pragma unroll
  for (int j = 0; j < 8; ++j) v[j] = (short)f2bf(a[j] * inv);
  *(bf16x8*)p = v;
  if (lane == 0) wout[row] = dot + fcb[0];
}

// ---------------- softmax: blocks 0..63 vw rows (196), 64..127 tw rows (64, masked) ----
__global__ void k_softmax(float* __restrict__ vwf, float* __restrict__ twf,
                          const int* __restrict__ tlen) {
  __shared__ float red[8];
  int tid = threadIdx.x;
  if (blockIdx.x < 64) {
    int b = blockIdx.x;
    float x = (tid < NV) ? vwf[b * NV + tid] : -1e30f;
    float m = x;
    for (int s = 1; s < 64; s <<= 1) m = fmaxf(m, __shfl_xor(m, s));
    if ((tid & 63) == 0) red[tid >> 6] = m;
    __syncthreads();
    m = fmaxf(fmaxf(red[0], red[1]), fmaxf(red[2], red[3]));
    float e = (tid < NV) ? expf(x - m) : 0.0f;
    float s = e;
    for (int st = 1; st < 64; st <<= 1) s += __shfl_xor(s, st);
    if ((tid & 63) == 0) red[4 + (tid >> 6)] = s;
    __syncthreads();
    s = red[4] + red[5] + red[6] + red[7];
    if (tid < NV) vwf[b * NV + tid] = e / s;
  } else {
    int b = blockIdx.x - 64;
    if (tid < 64) {
      int len = tlen[b];
      float x = twf[b * NT + tid];
      bool valid = tid < len;
      float xv = valid ? x : -1e30f;
      float m = xv;
      for (int s = 1; s < 64; s <<= 1) m = fmaxf(m, __shfl_xor(m, s));
      float e = valid ? expf(x - m) : 0.0f;
      float s = e;
      for (int st = 1; st < 64; st <<= 1) s += __shfl_xor(s, st);
      twf[b * NT + tid] = e / s;
    }
  }
}

// ---------------- MFMA sim kernel: one block (8 waves) per (b, q-pair) --------------
// r12 main loop; diag-only argmax epilogue (r15, measured 93 us).
__global__ __launch_bounds__(512, 4) void k_sim(
    const short* __restrict__ ve_bf, const short* __restrict__ te_bf,
    const float* __restrict__ vwf, const float* __restrict__ twf,
    float* __restrict__ out, int* __restrict__ gMT, int* __restrict__ gMV) {
  __shared__ short As[2][208 * 32];   // linear, 64B row stride
  __shared__ short Bs[2][128 * 32];
  __shared__ float colv[8][64];
  __shared__ int   coli[8][64];
  __shared__ float redp[8];
  int n = blockIdx.x;
  int xcd = n & 7, idx = n >> 3;
  int b = xcd * 8 + (idx & 7);     // b-fastest within XCD chunk (ve L2-resident)
  int qq = idx >> 3;               // 0..31
  int tid = threadIdx.x;
  int w = tid >> 6, lane = tid & 63, lg = lane >> 4, li = lane & 15;
  int qsel = w >> 2, wr = w & 3;
  int q = 2 * qq + qsel;
  const short* Abf = ve_bf + (size_t)b * NV * EDIM;
  const short* Bbf = te_bf + (size_t)qq * 128 * EDIM;  // rows 0-63: q0, 64-127: q1
  int fsw = (li + (li >> 2)) & 3;
  int nt = wr ? 3 : 4;
  int tbase = wr ? (1 + wr * 3) : 0;  // wr0:0-3, wr1:4-6, wr2:7-9, wr3:10-12

  const short* aSrc[2];
#pragma unroll
  for (int uu = 0; uu < 2; ++uu) {
    int u = uu * 512 + w * 64 + lane;
    int row = u >> 2;
    if (row > NV - 1) row = NV - 1;
    int seg = u & 3;
    int ss = seg ^ swz4(row);
    aSrc[uu] = Abf + (size_t)row * EDIM + ss * 8;
  }
  const short* bSrc;
  {
    int u = tid;                     // 512 units = 128 rows x 4 segs
    int row = u >> 2, seg = u & 3;
    int ss = seg ^ swz4(row);
    bSrc = Bbf + (size_t)row * EDIM + ss * 8;
  }

  auto stage = [&](int bb) {         // w0-4: 3 loads, w5-7: 2 loads
    short* Ad = &As[bb][0];
    short* Bd = &Bs[bb][0];
    gload16(bSrc, Bd + (w * 64) * 8);
    bSrc += 32;
#pragma unroll
    for (int uu = 0; uu < 2; ++uu) {
      int u0 = uu * 512 + w * 64;
      if (u0 < NV * 4) {
        gload16(aSrc[uu], Ad + u0 * 8);
        aSrc[uu] += 32;
      }
    }
  };

  f32x4 acc[4][4];
#pragma unroll
  for (int i = 0; i < 4; ++i)
#pragma unroll
    for (int j = 0; j < 4; ++j) acc[i][j] = (f32x4){0.f, 0.f, 0.f, 0.f};

  stage(0);
  int cur = 0;
  for (int kc = 0; kc < 16; ++kc) {
    __builtin_amdgcn_s_barrier();      // all waves done reading buf[cur^1]
    if (kc < 15) {
      stage(cur ^ 1);
      if (w <= 4) asm volatile("s_waitcnt vmcnt(3)" ::: "memory");
      else        asm volatile("s_waitcnt vmcnt(2)" ::: "memory");
    } else {
      asm volatile("s_waitcnt vmcnt(0)" ::: "memory");
    }
    __builtin_amdgcn_s_barrier();      // buf[cur] visible to all waves
    const short* Ab2 = &As[cur][0];
    const short* Bb2 = &Bs[cur][0];
    bf16x8 bfr[4];
#pragma unroll
    for (int j = 0; j < 4; ++j)
      bfr[j] = *(const bf16x8*)(Bb2 + (qsel * 64 + j * 16 + li) * 32 + (lg ^ fsw) * 8);
    __builtin_amdgcn_s_setprio(1);
#pragma unroll
    for (int i = 0; i < 4; ++i) {
      if (i < nt) {
        bf16x8 afr = *(const bf16x8*)(Ab2 + ((tbase + i) * 16 + li) * 32 + (lg ^ fsw) * 8);
#pragma unroll
        for (int j = 0; j < 4; ++j)
          acc[i][j] = __builtin_amdgcn_mfma_f32_16x16x32_bf16(afr, bfr[j], acc[i][j], 0, 0, 0);
      }
    }
    __builtin_amdgcn_s_setprio(0);
    cur ^= 1;
  }

  bool diag = (b == q);    // b == 2qq+qsel; per-wave uniform
  bool diagblk = (b >> 1) == qq;  // block contains a diagonal q (block-uniform)
  float ip = 0.f;

  if (diagblk) {
    // ---- full argmax path (indices + tie-break); only 64/2048 blocks
#pragma unroll
    for (int i = 0; i < 4; ++i) {
      if (i < nt) {
#pragma unroll
        for (int reg = 0; reg < 4; ++reg) {
          int v = (tbase + i) * 16 + lg * 4 + reg;
          float m = acc[i][0][reg];
          int ti = li;
#pragma unroll
          for (int j = 1; j < 4; ++j) {
            float vv = acc[i][j][reg];
            int t = j * 16 + li;
            if (vv > m) { m = vv; ti = t; }   // t ascending -> first-index kept
          }
          for (int d = 1; d < 16; d <<= 1) {  // within li-group (same row)
            float om = __shfl_xor(m, d);
            int oi = __shfl_xor(ti, d);
            if (om > m || (om == m && oi < ti)) { m = om; ti = oi; }
          }
          if (li == 0 && v < NV) {
            ip += vwf[b * NV + v] * m;
            if (diag) gMT[b * NV + v] = b * NT + ti;
          }
        }
      }
    }
    // col (over v) max+argmax
    float cm[4]; int cv[4];
#pragma unroll
    for (int j = 0; j < 4; ++j) { cm[j] = -3.0e38f; cv[j] = 0; }
#pragma unroll
    for (int i = 0; i < 4; ++i) {
      if (i < nt) {
#pragma unroll
        for (int reg = 0; reg < 4; ++reg) {
          int v = (tbase + i) * 16 + lg * 4 + reg;
          bool ok = v < NV;
#pragma unroll
          for (int j = 0; j < 4; ++j) {
            float s = ok ? acc[i][j][reg] : -3.0e38f;
            if (s > cm[j]) { cm[j] = s; cv[j] = v; }  // v ascending per lane
          }
        }
      }
    }
#pragma unroll
    for (int j = 0; j < 4; ++j) {
      for (int d = 16; d < 64; d <<= 1) {   // mixes lg groups (same col)
        float om = __shfl_xor(cm[j], d);
        int ov = __shfl_xor(cv[j], d);
        if (om > cm[j] || (om == cm[j] && ov < cv[j])) { cm[j] = om; cv[j] = ov; }
      }
      if (lg == 0) { colv[w][j * 16 + li] = cm[j]; coli[w][j * 16 + li] = cv[j]; }
    }
  } else {
    // ---- value-only path (fmax trees, no index juggling)
#pragma unroll
    for (int i = 0; i < 4; ++i) {
      if (i < nt) {
#pragma unroll
        for (int reg = 0; reg < 4; ++reg) {
          int v = (tbase + i) * 16 + lg * 4 + reg;
          float m = fmaxf(fmaxf(acc[i][0][reg], acc[i][1][reg]),
                          fmaxf(acc[i][2][reg], acc[i][3][reg]));
          for (int d = 1; d < 16; d <<= 1) m = fmaxf(m, __shfl_xor(m, d));
          if (li == 0 && v < NV) ip += vwf[b * NV + v] * m;
        }
      }
    }
    float cm[4];
#pragma unroll
    for (int j = 0; j < 4; ++j) cm[j] = -3.0e38f;
#pragma unroll
    for (int i = 0; i < 4; ++i) {
      if (i < nt) {
#pragma unroll
      for (int reg = 0; reg < 4; ++reg) {
          int v = (tbase + i) * 16 + lg * 4 + reg;
          bool ok = v < NV;
#pragma unroll
          for (int j = 0; j < 4; ++j)
            cm[j] = fmaxf(cm[j], ok ? acc[i][j][reg] : -3.0e38f);
        }
      }
    }
#pragma unroll
    for (int j = 0; j < 4; ++j) {
      for (int d = 16; d < 64; d <<= 1) cm[j] = fmaxf(cm[j], __shfl_xor(cm[j], d));
      if (lg == 0) colv[w][j * 16 + li] = cm[j];
    }
  }
  for (int d = 1; d < 64; d <<= 1) ip += __shfl_xor(ip, d);
  if (lane == 0) redp[w] = ip;
  __syncthreads();
  if (tid < 128) {   // tid>>6==0 -> q0 (colv 0-3), ==1 -> q1 (colv 4-7)
    int qs = tid >> 6, t = tid & 63;
    int qe = 2 * qq + qs;
    float m = colv[qs * 4][t];
    if (diagblk) {
      int bi = coli[qs * 4][t];
#pragma unroll
      for (int w2 = 1; w2 < 4; ++w2) {
        float om = colv[qs * 4 + w2][t];
        int ov = coli[qs * 4 + w2][t];
        if (om > m || (om == m && ov < bi)) { m = om; bi = ov; }
      }
      if (b == qe) gMV[b * NT + t] = b * NV + bi;
    } else {
#pragma unroll
      for (int w2 = 1; w2 < 4; ++w2) m = fmaxf(m, colv[qs * 4 + w2][t]);
    }
    float p = twf[qe * NT + t] * m;
    for (int d = 1; d < 64; d <<= 1) p += __shfl_xor(p, d);
    if ((tid & 63) == 0) out[4096 + b * 64 + qe] = p;
  }
  if (tid == 0) {
    out[b * 64 + 2 * qq]     = redp[0] + redp[1] + redp[2] + redp[3];
    out[b * 64 + 2 * qq + 1] = redp[4] + redp[5] + redp[6] + redp[7];
  }
}

// ------- transpose-materialize (K-chunk-tiled dst [K/32][512][32]) + fused stats ----
__global__ void k_materialize(const short* __restrict__ ve_bf, const short* __restrict__ te_bf,
                              const int* __restrict__ gMT, const int* __restrict__ gMV,
                              const float* __restrict__ vwf, const float* __restrict__ twf,
                              short* __restrict__ tTw, short* __restrict__ mvT,
                              short* __restrict__ vTw, short* __restrict__ mtT,
                              float* __restrict__ statPart) {
  int z = blockIdx.z;
  int at = blockIdx.x, ct = blockIdx.y;
  int K = (z == 2 || z == 3) ? MROWS_V : MROWS_T;
  if (at * 64 >= K) return;
  const short* src; const int* g = 0; short* dst;
  bool applyW;
  const float* wS = (z <= 1) ? twf : vwf;
  if (z == 0)      { src = te_bf; dst = tTw; applyW = true;  }
  else if (z == 1) { src = ve_bf; g = gMV; dst = mvT; applyW = false; }
  else if (z == 2) { src = ve_bf; dst = vTw; applyW = true;  }
  else             { src = te_bf; g = gMT; dst = mtT; applyW = false; }
  __shared__ float tile[64][67];
  __shared__ float wrow[64];
  int tid = threadIdx.x;
  for (int u = tid; u < 512; u += 256) {
    int a = u >> 3, cseg = (u & 7) << 3;
    int ga = at * 64 + a;
    int row = g ? g[ga] : ga;
    bf16x8 vv = *(const bf16x8*)(src + (size_t)row * EDIM + ct * 64 + cseg);
#pragma unroll
    for (int j = 0; j < 8; j++) tile[a][cseg + j] = bf2f(vv[j]);
    if ((u & 7) == 0) wrow[a] = wS[ga];
  }
  __syncthreads();
  for (int u = tid; u < 512; u += 256) {
    int c = u >> 3, aseg = (u & 7) << 3;
    bf16x8 ov;
#pragma unroll
    for (int j = 0; j < 8; j++) {
      float x = tile[aseg + j][c];
      if (applyW) x *= wrow[aseg + j];
      ov[j] = (short)f2bf(x);
    }
    int kchunk = at * 2 + (aseg >> 5);   // K-chunk-tiled: [K/32][512][32]
    *(bf16x8*)(dst + ((size_t)kchunk * 512 + ct * 64 + c) * 32 + (aseg & 31)) = ov;
  }
  // ---- fused stats partials: 4 threads per column, 16 a's each
  int cl = tid >> 2, part = tid & 3;
  float s = 0, ssq = 0, sw = 0;
  for (int a = part * 16; a < part * 16 + 16; ++a) {
    float x = tile[a][cl];
    s += x; ssq += x * x; sw += wrow[a] * x;
  }
  for (int d = 1; d < 4; d <<= 1) {   // 4 consecutive lanes share a column
    s += __shfl_xor(s, d); ssq += __shfl_xor(ssq, d); sw += __shfl_xor(sw, d);
  }
  if (part == 0) {
    int cbase = (z == 0) ? 0 : (z == 1) ? 64 : (z == 2) ? 128 : 324;
    size_t sidx = ((size_t)(cbase + at) * 512 + ct * 64 + cl) * 3;
    statPart[sidx] = s; statPart[sidx + 1] = ssq; statPart[sidx + 2] = sw;
  }
}

__global__ void k_statfin(const float* __restrict__ statPart, float* __restrict__ stats) {
  int m = blockIdx.x, c = threadIdx.x;
  int R = (m < 2) ? MROWS_T : MROWS_V;
  int nchunk = (m < 2) ? 64 : 196;
  int base = (m == 0) ? 0 : (m == 1) ? 64 : (m == 2) ? 128 : 324;
  float s = 0, ss = 0, sw = 0;
  for (int ch = 0; ch < nchunk; ch++) {
    size_t idx = ((size_t)(base + ch) * 512 + c) * 3;
    s += statPart[idx]; ss += statPart[idx + 1]; sw += statPart[idx + 2];
  }
  float mean = s / R;
  float var = (ss - s * mean) / (R - 1);  // ddof=1
  float rstd = 1.0f / sqrtf(var);
  stats[(m * 3 + 0) * 512 + c] = mean;
  stats[(m * 3 + 1) * 512 + c] = rstd;
  stats[(m * 3 + 2) * 512 + c] = sw;
}

// ------- MFMA weighted GEMM on K-chunk-tiled operands: 128x128 tile, 8 waves -------
// Per chunk, block reads 8KB+8KB fully contiguous slabs from [K/32][512][32].
__global__ __launch_bounds__(512, 2) void k_wgemm2(
    const short* __restrict__ tTw, const short* __restrict__ mvT,
    const short* __restrict__ vTw, const short* __restrict__ mtT,
    float* __restrict__ Spart) {
  __shared__ short As[2][128 * 32];
  __shared__ short Bs[2][128 * 32];
  int c0 = blockIdx.x * 128, d0 = blockIdx.y * 128;
  int z = blockIdx.z;                 // 0..15
  int which = z >> 3, slice = z & 7;
  const short* A = which ? vTw : tTw;
  const short* B = which ? mtT : mvT;
  int K = which ? MROWS_V : MROWS_T;
  int nch = (K >> 3) >> 5;            // 49 or 16 chunks of 32
  size_t a0c = (size_t)slice * nch;   // starting K-chunk
  int tid = threadIdx.x;
  int w = tid >> 6, lane = tid & 63, lg = lane >> 4, li = lane & 15;
  int fsw = (li + (li >> 2)) & 3;

  const short* aSrc; const short* bSrc;
  {
    int row = tid >> 2, seg = tid & 3;   // 512 units = 128 rows x 4 segs
    int ss = seg ^ swz4(row);
    aSrc = A + (a0c * 512 + (size_t)(c0 + row)) * 32 + ss * 8;
    bSrc = B + (a0c * 512 + (size_t)(d0 + row)) * 32 + ss * 8;
  }

  auto stage = [&](int bb) {           // 2 loads/wave
    gload16(aSrc, &As[bb][0] + (w * 64) * 8);
    aSrc += 512 * 32;
    gload16(bSrc, &Bs[bb][0] + (w * 64) * 8);
    bSrc += 512 * 32;
  };

  f32x4 acc[8];
#pragma unroll
  for (int j = 0; j < 8; ++j) acc[j] = (f32x4){0.f, 0.f, 0.f, 0.f};

  stage(0);
  int cur = 0;
  for (int ch = 0; ch < nch; ++ch) {
    __builtin_amdgcn_s_barrier();
    if (ch < nch - 1) {
      stage(cur ^ 1);
      asm volatile("s_waitcnt vmcnt(2)" ::: "memory");
    } else {
      asm volatile("s_waitcnt vmcnt(0)" ::: "memory");
    }
    __builtin_amdgcn_s_barrier();
    const short* Ab = &As[cur][0];
    const short* Bb = &Bs[cur][0];
    bf16x8 afr = *(const bf16x8*)(Ab + (w * 16 + li) * 32 + (lg ^ fsw) * 8);
    __builtin_amdgcn_s_setprio(1);
#pragma unroll
    for (int j = 0; j < 8; ++j) {
      bf16x8 bfr = *(const bf16x8*)(Bb + (j * 16 + li) * 32 + (lg ^ fsw) * 8);
      acc[j] = __builtin_amdgcn_mfma_f32_16x16x32_bf16(afr, bfr, acc[j], 0, 0, 0);
    }
    __builtin_amdgcn_s_setprio(0);
    cur ^= 1;
  }
  float* outp = Spart + (size_t)z * 512 * 512;
#pragma unroll
  for (int j = 0; j < 8; ++j) {
    int d = d0 + j * 16 + li;
#pragma unroll
    for (int reg = 0; reg < 4; ++reg)
      outp[(size_t)(c0 + w * 16 + lg * 4 + reg) * 512 + d] = acc[j][reg];
  }
}

// ---------------- assemble c = (c1+c2)/2 from closed form; loss partials ----------
__global__ void k_assemble(const float* __restrict__ Spart, const float* __restrict__ stats,
                           float* __restrict__ lossPart) {
  int c = blockIdx.x, tid = threadIdx.x;
  float muT = stats[0 * 512 + c], rsT = stats[1 * 512 + c], swT = stats[2 * 512 + c];
  float muV = stats[6 * 512 + c], rsV = stats[7 * 512 + c], swV = stats[8 * 512 + c];
  const float W = 64.0f, invB = 1.0f / 64.0f;
  float on = 0, off = 0;
  for (int d = tid; d < 512; d += 256) {
    float s1 = 0, s2 = 0;
    for (int sl = 0; sl < 8; sl++) {
      s1 += Spart[((size_t)sl * 512 + c) * 512 + d];
      s2 += Spart[((size_t)(8 + sl) * 512 + c) * 512 + d];
    }
    float muMV = stats[3 * 512 + d], rsMV = stats[4 * 512 + d], swMV = stats[5 * 512 + d];
    float muMT = stats[9 * 512 + d], rsMT = stats[10 * 512 + d], swMT = stats[11 * 512 + d];
    float c1 = (s1 - muT * swMV - muMV * swT + muT * muMV * W) * rsT * rsMV * invB;
    float c2 = (s2 - muV * swMT - muMT * swV + muV * muMT * W) * rsV * rsMT * invB;
    float cc = 0.5f * (c1 + c2);
    if (d == c) { float dd = cc - 1.0f; on += dd * dd; }
    else off += cc * cc;
  }
  __shared__ float r1[4], r2[4];
  for (int s = 1; s < 64; s <<= 1) { on += __shfl_xor(on, s); off += __shfl_xor(off, s); }
  if ((tid & 63) == 0) { r1[tid >> 6] = on; r2[tid >> 6] = off; }
  __syncthreads();
  if (tid == 0) {
    lossPart[c * 2] = r1[0] + r1[1] + r1[2] + r1[3];
    lossPart[c * 2 + 1] = r2[0] + r2[1] + r2[2] + r2[3];
  }
}

__global__ void k_loss(const float* __restrict__ lossPart, float* __restrict__ out) {
  int tid = threadIdx.x;
  float on = 0, off = 0;
  for (int i = tid; i < 512; i += 256) { on += lossPart[2 * i]; off += lossPart[2 * i + 1]; }
  __shared__ float r1[4], r2[4];
  for (int s = 1; s < 64; s <<= 1) { on += __shfl_xor(on, s); off += __shfl_xor(off, s); }
  if ((tid & 63) == 0) { r1[tid >> 6] = on; r2[tid >> 6] = off; }
  __syncthreads();
  if (tid == 0)
    out[8192] = 0.1f * ((r1[0] + r1[1] + r1[2] + r1[3]) +
                        0.06f * (r2[0] + r2[1] + r2[2] + r2[3]));
}

extern "C" void kernel_launch(void* const* d_in, const int* in_sizes, int n_in,
                              void* d_out, int out_size, void* d_ws, size_t ws_size,
                              hipStream_t stream) {
  (void)in_sizes; (void)n_in; (void)out_size; (void)ws_size;
  const float* v_tok  = (const float*)d_in[1];
  const float* t_tok  = (const float*)d_in[3];
  const float* Wv_tok = (const float*)d_in[8];
  const float* Wt_tok = (const float*)d_in[10];
  const float* bv_tok = (const float*)d_in[9];
  const float* bt_tok = (const float*)d_in[11];
  const float* wv_fc  = (const float*)d_in[12];
  const float* bv_fc  = (const float*)d_in[13];
  const float* wt_fc  = (const float*)d_in[14];
  const float* bt_fc  = (const float*)d_in[15];
  const int*   tlen   = (const int*)d_in[16];
  float* out = (float*)d_out;

  char* wsb = (char*)d_ws;
  short* v_tok_bf = (short*)wsb;                       // 9,633,792 sh
  short* t_tok_bf = v_tok_bf + (size_t)9633792;        // 3,145,728 sh
  short* WvT      = t_tok_bf + (size_t)3145728;        //   393,216 sh
  short* WtT      = WvT + (size_t)393216;              //   393,216 sh
  short* tTw = (short*)wsb;                            // 512*4096 (alias, phase2)
  short* mvT = tTw + (size_t)2097152;                  // 512*4096
  short* vTw = mvT + (size_t)2097152;                  // 512*12544
  short* ve_bf = (short*)(wsb + 27131904);             // 6,422,528 sh
  short* te_bf = ve_bf + (size_t)6422528;              // 2,097,152 sh
  float* Spart = (float*)(wsb + 27131904);             // 16*512*512 f (alias, phase-b)
  short* mtT = (short*)(wsb + 44171264);               // 512*12544
  float* vwf = (float*)(wsb + 57016320);               // 12544
  float* twf = vwf + 12544;                            // 4096
  int* gMT = (int*)(twf + 4096);                       // 12544
  int* gMV = gMT + 12544;                              // 4096
  float* statPart = (float*)(gMV + 4096);              // 520*512*3 f (3.2 MB)
  float* stats = statPart + (size_t)520 * 512 * 3;     // 12*512
  float* lossPart = stats + 6144;                      // 1024

  k_prep<<<7008, 256, 0, stream>>>(v_tok, v_tok_bf, 1204224, t_tok, t_tok_bf, 393216,
                                   Wv_tok, Wt_tok, WvT, WtT);
  k_proj_mfma2<<<dim3(4, 130), 256, 0, stream>>>(v_tok_bf, t_tok_bf, WvT, WtT,
                                                 bv_tok, bt_tok, ve_bf, te_bf);
  k_normfc2<<<4160, 256, 0, stream>>>(ve_bf, te_bf, wv_fc, wt_fc, bv_fc, bt_fc, vwf, twf);
  k_softmax<<<128, 256, 0, stream>>>(vwf, twf, tlen);
  k_sim<<<2048, 512, 0, stream>>>(ve_bf, te_bf, vwf, twf, out, gMT, gMV);
  k_materialize<<<dim3(196, 8, 4), 256, 0, stream>>>(ve_bf, te_bf, gMT, gMV, vwf, twf,
                                                     tTw, mvT, vTw, mtT, statPart);
  k_statfin<<<4, 512, 0, stream>>>(statPart, stats);
  k_wgemm2<<<dim3(4, 4, 16), 512, 0, stream>>>(tTw, mvT, vTw, mtT, Spart);
  k_assemble<<<512, 256, 0, stream>>>(Spart, stats, lossPart);
  k_loss<<<1, 256, 0, stream>>>(lossPart, out);
}

// Round 20
// 218.489 us; speedup vs baseline: 1.6766x; 1.1311x over previous
//
#include <hip/hip_runtime.h>
#include <cstddef>

#define EDIM 512
#define KDIM 768
#define NB 64
#define NV 196
#define NT 64
#define MROWS_V (NB * NV) /* 12544 */
#define MROWS_T (NB * NT) /* 4096  */

typedef __attribute__((ext_vector_type(8))) short bf16x8;
typedef __attribute__((ext_vector_type(4))) float f32x4;

static __device__ inline unsigned short f2bf(float f) {  // round-to-nearest-even
  unsigned u = __float_as_uint(f);
  unsigned r = (u + 0x7fff + ((u >> 16) & 1)) >> 16;
  return (unsigned short)r;
}
static __device__ inline float bf2f(short s) {
  return __uint_as_float(((unsigned)(unsigned short)s) << 16);
}
// seg swizzle: for row-tiles read at fixed li, spreads bank-starts
static __device__ __forceinline__ int swz4(int r) { return (r + (r >> 2)) & 3; }

// async global->LDS, 16B per lane; LDS dest = wave-uniform base + lane*16
static __device__ __forceinline__ void gload16(const void* g, void* l) {
  __builtin_amdgcn_global_load_lds(
      (const __attribute__((address_space(1))) void*)g,
      (__attribute__((address_space(3))) void*)l, 16, 0, 0);
}

// ------- merged prep: fp32->bf16 convert (v_tok,t_tok) + W transpose->bf16 -------
__global__ void k_prep(const float* __restrict__ va, short* __restrict__ vo, int na8,
                       const float* __restrict__ ta, short* __restrict__ to, int nb8,
                       const float* __restrict__ W0, const float* __restrict__ W1,
                       short* __restrict__ T0, short* __restrict__ T1) {
  __shared__ float tile[32][33];
  int blk = blockIdx.x;
  int tid = threadIdx.x;
  if (blk < 6240) {
    int i = blk * 256 + tid;
    const float* in; short* outp; int idx;
    if (i < na8) { in = va; outp = vo; idx = i; }
    else { idx = i - na8; if (idx >= nb8) return; in = ta; outp = to; }
    float4 a = *(const float4*)(in + (size_t)idx * 8);
    float4 b = *(const float4*)(in + (size_t)idx * 8 + 4);
    bf16x8 v;
    v[0] = (short)f2bf(a.x); v[1] = (short)f2bf(a.y);
    v[2] = (short)f2bf(a.z); v[3] = (short)f2bf(a.w);
    v[4] = (short)f2bf(b.x); v[5] = (short)f2bf(b.y);
    v[6] = (short)f2bf(b.z); v[7] = (short)f2bf(b.w);
    *(bf16x8*)(outp + (size_t)idx * 8) = v;
  } else {
    int z = blk - 6240;            // 0..767 = 24 x 16 x 2
    int bx = z % 24, by = (z / 24) % 16, bz = z / 384;
    const float* W = bz ? W1 : W0;
    short*       T = bz ? T1 : T0;
    int k0 = bx * 32, n0 = by * 32;
    int tx = tid & 31, ty = tid >> 5;
    for (int i = ty; i < 32; i += 8)
      tile[i][tx] = W[(size_t)(k0 + i) * EDIM + n0 + tx];
    __syncthreads();
    for (int i = ty; i < 32; i += 8)
      T[(size_t)(n0 + i) * KDIM + k0 + tx] = (short)f2bf(tile[tx][i]);
  }
}

// ---------- MFMA projection (merged v+t), 128x128 tile: 16 MFMA/wave/kc ----
__global__ __launch_bounds__(256, 4) void k_proj_mfma2(
    const short* __restrict__ vX, const short* __restrict__ tX,
    const short* __restrict__ WvT, const short* __restrict__ WtT,
    const float* __restrict__ vb, const float* __restrict__ tb,
    short* __restrict__ vout, short* __restrict__ tout) {
  __shared__ short As[2][128 * 32];
  __shared__ short Bs[2][128 * 32];
  int y = blockIdx.y;
  const short* Xbf; const short* WT; const float* bias; short* Mbf; int r0;
  if (y < 98) { Xbf = vX; WT = WvT; bias = vb; Mbf = vout; r0 = y * 128; }
  else        { Xbf = tX; WT = WtT; bias = tb; Mbf = tout; r0 = (y - 98) * 128; }
  int n0 = blockIdx.x * 128;
  int tid = threadIdx.x;
  int w = tid >> 6, lane = tid & 63, lg = lane >> 4, li = lane & 15;
  int fsw = (li + (li >> 2)) & 3;

  const short* aSrc[2];
  const short* bSrc[2];
#pragma unroll
  for (int uu = 0; uu < 2; ++uu) {
    int u = uu * 256 + w * 64 + lane;
    int row = u >> 2, seg = u & 3;
    int ss = seg ^ swz4(row);
    aSrc[uu] = Xbf + (size_t)(r0 + row) * KDIM + ss * 8;
    bSrc[uu] = WT + (size_t)(n0 + row) * KDIM + ss * 8;
  }

  auto stage = [&](int bb) {
    short* Ad = &As[bb][0];
    short* Bd = &Bs[bb][0];
#pragma unroll
    for (int uu = 0; uu < 2; ++uu) {
      gload16(aSrc[uu], Ad + (uu * 256 + w * 64) * 8);
      aSrc[uu] += 32;
      gload16(bSrc[uu], Bd + (uu * 256 + w * 64) * 8);
      bSrc[uu] += 32;
    }
  };

  f32x4 acc[2][8];
#pragma unroll
  for (int i = 0; i < 2; ++i)
#pragma unroll
    for (int j = 0; j < 8; ++j) acc[i][j] = (f32x4){0.f, 0.f, 0.f, 0.f};

  stage(0);   // 4 loads in flight
  int cur = 0;
  const int NKC = KDIM / 32;  // 24
  for (int kc = 0; kc < NKC; ++kc) {
    __builtin_amdgcn_s_barrier();
    if (kc < NKC - 1) {
      stage(cur ^ 1);
      asm volatile("s_waitcnt vmcnt(4)" ::: "memory");
    } else {
      asm volatile("s_waitcnt vmcnt(0)" ::: "memory");
    }
    __builtin_amdgcn_s_barrier();
    const short* Ab = &As[cur][0];
    const short* Bb = &Bs[cur][0];
    bf16x8 bfr[8];
#pragma unroll
    for (int j = 0; j < 8; ++j)
      bfr[j] = *(const bf16x8*)(Bb + (j * 16 + li) * 32 + (lg ^ fsw) * 8);
    __builtin_amdgcn_s_setprio(1);
#pragma unroll
    for (int i = 0; i < 2; ++i) {
      bf16x8 afr = *(const bf16x8*)(Ab + ((w * 2 + i) * 16 + li) * 32 + (lg ^ fsw) * 8);
#pragma unroll
      for (int j = 0; j < 8; ++j)
        acc[i][j] = __builtin_amdgcn_mfma_f32_16x16x32_bf16(afr, bfr[j], acc[i][j], 0, 0, 0);
    }
    __builtin_amdgcn_s_setprio(0);
    cur ^= 1;
  }
#pragma unroll
  for (int j = 0; j < 8; ++j) {
    int n = n0 + j * 16 + li;
    float bb = bias[n];
#pragma unroll
    for (int i = 0; i < 2; ++i)
#pragma unroll
      for (int reg = 0; reg < 4; ++reg)
        Mbf[(size_t)(r0 + (w * 2 + i) * 16 + lg * 4 + reg) * EDIM + n] =
            (short)f2bf(acc[i][j][reg] + bb);
  }
}

// ------- per-row (bf16 in place): fc scalar + l2 normalize; merged v+t -------
__global__ void k_normfc2(short* __restrict__ vM, short* __restrict__ tM,
                          const float* __restrict__ vfcw, const float* __restrict__ tfcw,
                          const float* __restrict__ vfcb, const float* __restrict__ tfcb,
                          float* __restrict__ vwout, float* __restrict__ twout) {
  int blk = blockIdx.x;
  short* Mbf; const float* fcw; const float* fcb; float* wout; int row;
  if (blk < 3136) { Mbf = vM; fcw = vfcw; fcb = vfcb; wout = vwout;
                    row = blk * 4 + (threadIdx.x >> 6); if (row >= 12544) return; }
  else            { Mbf = tM; fcw = tfcw; fcb = tfcb; wout = twout;
                    row = (blk - 3136) * 4 + (threadIdx.x >> 6); if (row >= 4096) return; }
  int lane = threadIdx.x & 63;
  short* p = Mbf + (size_t)row * EDIM + lane * 8;
  bf16x8 v = *(bf16x8*)p;
  float4 w0 = *(const float4*)(fcw + lane * 8);
  float4 w1 = *(const float4*)(fcw + lane * 8 + 4);
  float a[8];
#pragma unroll
  for (int j = 0; j < 8; ++j) a[j] = bf2f(v[j]);
  float dot = a[0] * w0.x + a[1] * w0.y + a[2] * w0.z + a[3] * w0.w +
              a[4] * w1.x + a[5] * w1.y + a[6] * w1.z + a[7] * w1.w;
  float ss = a[0] * a[0] + a[1] * a[1] + a[2] * a[2] + a[3] * a[3] +
             a[4] * a[4] + a[5] * a[5] + a[6] * a[6] + a[7] * a[7];
  for (int s = 1; s < 64; s <<= 1) {
    dot += __shfl_xor(dot, s);
    ss += __shfl_xor(ss, s);
  }
  float inv = 1.0f / fmaxf(sqrtf(ss), 1e-12f);
#pragma unroll
  for (int j = 0; j < 8; ++j) v[j] = (short)f2bf(a[j] * inv);
  *(bf16x8*)p = v;
  if (lane == 0) wout[row] = dot + fcb[0];
}

// ---------------- softmax: blocks 0..63 vw rows (196), 64..127 tw rows (64, masked) ----
__global__ void k_softmax(float* __restrict__ vwf, float* __restrict__ twf,
                          const int* __restrict__ tlen) {
  __shared__ float red[8];
  int tid = threadIdx.x;
  if (blockIdx.x < 64) {
    int b = blockIdx.x;
    float x = (tid < NV) ? vwf[b * NV + tid] : -1e30f;
    float m = x;
    for (int s = 1; s < 64; s <<= 1) m = fmaxf(m, __shfl_xor(m, s));
    if ((tid & 63) == 0) red[tid >> 6] = m;
    __syncthreads();
    m = fmaxf(fmaxf(red[0], red[1]), fmaxf(red[2], red[3]));
    float e = (tid < NV) ? expf(x - m) : 0.0f;
    float s = e;
    for (int st = 1; st < 64; st <<= 1) s += __shfl_xor(s, st);
    if ((tid & 63) == 0) red[4 + (tid >> 6)] = s;
    __syncthreads();
    s = red[4] + red[5] + red[6] + red[7];
    if (tid < NV) vwf[b * NV + tid] = e / s;
  } else {
    int b = blockIdx.x - 64;
    if (tid < 64) {
      int len = tlen[b];
      float x = twf[b * NT + tid];
      bool valid = tid < len;
      float xv = valid ? x : -1e30f;
      float m = xv;
      for (int s = 1; s < 64; s <<= 1) m = fmaxf(m, __shfl_xor(m, s));
      float e = valid ? expf(x - m) : 0.0f;
      float s = e;
      for (int st = 1; st < 64; st <<= 1) s += __shfl_xor(s, st);
      twf[b * NT + tid] = e / s;
    }
  }
}

// ---------------- MFMA sim kernel: one block (8 waves) per (b, q-pair) --------------
// r12 main loop; diag-only argmax epilogue (r15, measured 93 us).
__global__ __launch_bounds__(512, 4) void k_sim(
    const short* __restrict__ ve_bf, const short* __restrict__ te_bf,
    const float* __restrict__ vwf, const float* __restrict__ twf,
    float* __restrict__ out, int* __restrict__ gMT, int* __restrict__ gMV) {
  __shared__ short As[2][208 * 32];   // linear, 64B row stride
  __shared__ short Bs[2][128 * 32];
  __shared__ float colv[8][64];
  __shared__ int   coli[8][64];
  __shared__ float redp[8];
  int n = blockIdx.x;
  int xcd = n & 7, idx = n >> 3;
  int b = xcd * 8 + (idx & 7);     // b-fastest within XCD chunk (ve L2-resident)
  int qq = idx >> 3;               // 0..31
  int tid = threadIdx.x;
  int w = tid >> 6, lane = tid & 63, lg = lane >> 4, li = lane & 15;
  int qsel = w >> 2, wr = w & 3;
  int q = 2 * qq + qsel;
  const short* Abf = ve_bf + (size_t)b * NV * EDIM;
  const short* Bbf = te_bf + (size_t)qq * 128 * EDIM;  // rows 0-63: q0, 64-127: q1
  int fsw = (li + (li >> 2)) & 3;
  int nt = wr ? 3 : 4;
  int tbase = wr ? (1 + wr * 3) : 0;  // wr0:0-3, wr1:4-6, wr2:7-9, wr3:10-12

  const short* aSrc[2];
#pragma unroll
  for (int uu = 0; uu < 2; ++uu) {
    int u = uu * 512 + w * 64 + lane;
    int row = u >> 2;
    if (row > NV - 1) row = NV - 1;
    int seg = u & 3;
    int ss = seg ^ swz4(row);
    aSrc[uu] = Abf + (size_t)row * EDIM + ss * 8;
  }
  const short* bSrc;
  {
    int u = tid;                     // 512 units = 128 rows x 4 segs
    int row = u >> 2, seg = u & 3;
    int ss = seg ^ swz4(row);
    bSrc = Bbf + (size_t)row * EDIM + ss * 8;
  }

  auto stage = [&](int bb) {         // w0-4: 3 loads, w5-7: 2 loads
    short* Ad = &As[bb][0];
    short* Bd = &Bs[bb][0];
    gload16(bSrc, Bd + (w * 64) * 8);
    bSrc += 32;
#pragma unroll
    for (int uu = 0; uu < 2; ++uu) {
      int u0 = uu * 512 + w * 64;
      if (u0 < NV * 4) {
        gload16(aSrc[uu], Ad + u0 * 8);
        aSrc[uu] += 32;
      }
    }
  };

  f32x4 acc[4][4];
#pragma unroll
  for (int i = 0; i < 4; ++i)
#pragma unroll
    for (int j = 0; j < 4; ++j) acc[i][j] = (f32x4){0.f, 0.f, 0.f, 0.f};

  stage(0);
  int cur = 0;
  for (int kc = 0; kc < 16; ++kc) {
    __builtin_amdgcn_s_barrier();      // all waves done reading buf[cur^1]
    if (kc < 15) {
      stage(cur ^ 1);
      if (w <= 4) asm volatile("s_waitcnt vmcnt(3)" ::: "memory");
      else        asm volatile("s_waitcnt vmcnt(2)" ::: "memory");
    } else {
      asm volatile("s_waitcnt vmcnt(0)" ::: "memory");
    }
    __builtin_amdgcn_s_barrier();      // buf[cur] visible to all waves
    const short* Ab2 = &As[cur][0];
    const short* Bb2 = &Bs[cur][0];
    bf16x8 bfr[4];
#pragma unroll
    for (int j = 0; j < 4; ++j)
      bfr[j] = *(const bf16x8*)(Bb2 + (qsel * 64 + j * 16 + li) * 32 + (lg ^ fsw) * 8);
    __builtin_amdgcn_s_setprio(1);
#pragma unroll
    for (int i = 0; i < 4; ++i) {
      if (i < nt) {
        bf16x8 afr = *(const bf16x8*)(Ab2 + ((tbase + i) * 16 + li) * 32 + (lg ^ fsw) * 8);
#pragma unroll
        for (int j = 0; j < 4; ++j)
          acc[i][j] = __builtin_amdgcn_mfma_f32_16x16x32_bf16(afr, bfr[j], acc[i][j], 0, 0, 0);
      }
    }
    __builtin_amdgcn_s_setprio(0);
    cur ^= 1;
  }

  bool diag = (b == q);    // b == 2qq+qsel; per-wave uniform
  bool diagblk = (b >> 1) == qq;  // block contains a diagonal q (block-uniform)
  float ip = 0.f;

  if (diagblk) {
    // ---- full argmax path (indices + tie-break); only 64/2048 blocks
#pragma unroll
    for (int i = 0; i < 4; ++i) {
      if (i < nt) {
#pragma unroll
        for (int reg = 0; reg < 4; ++reg) {
          int v = (tbase + i) * 16 + lg * 4 + reg;
          float m = acc[i][0][reg];
          int ti = li;
#pragma unroll
          for (int j = 1; j < 4; ++j) {
            float vv = acc[i][j][reg];
            int t = j * 16 + li;
            if (vv > m) { m = vv; ti = t; }   // t ascending -> first-index kept
          }
          for (int d = 1; d < 16; d <<= 1) {  // within li-group (same row)
            float om = __shfl_xor(m, d);
            int oi = __shfl_xor(ti, d);
            if (om > m || (om == m && oi < ti)) { m = om; ti = oi; }
          }
          if (li == 0 && v < NV) {
            ip += vwf[b * NV + v] * m;
            if (diag) gMT[b * NV + v] = b * NT + ti;
          }
        }
      }
    }
    // col (over v) max+argmax
    float cm[4]; int cv[4];
#pragma unroll
    for (int j = 0; j < 4; ++j) { cm[j] = -3.0e38f; cv[j] = 0; }
#pragma unroll
    for (int i = 0; i < 4; ++i) {
      if (i < nt) {
#pragma unroll
        for (int reg = 0; reg < 4; ++reg) {
          int v = (tbase + i) * 16 + lg * 4 + reg;
          bool ok = v < NV;
#pragma unroll
          for (int j = 0; j < 4; ++j) {
            float s = ok ? acc[i][j][reg] : -3.0e38f;
            if (s > cm[j]) { cm[j] = s; cv[j] = v; }  // v ascending per lane
          }
        }
      }
    }
#pragma unroll
    for (int j = 0; j < 4; ++j) {
      for (int d = 16; d < 64; d <<= 1) {   // mixes lg groups (same col)
        float om = __shfl_xor(cm[j], d);
        int ov = __shfl_xor(cv[j], d);
        if (om > cm[j] || (om == cm[j] && ov < cv[j])) { cm[j] = om; cv[j] = ov; }
      }
      if (lg == 0) { colv[w][j * 16 + li] = cm[j]; coli[w][j * 16 + li] = cv[j]; }
    }
  } else {
    // ---- value-only path (fmax trees, no index juggling)
#pragma unroll
    for (int i = 0; i < 4; ++i) {
      if (i < nt) {
#pragma unroll
        for (int reg = 0; reg < 4; ++reg) {
          int v = (tbase + i) * 16 + lg * 4 + reg;
          float m = fmaxf(fmaxf(acc[i][0][reg], acc[i][1][reg]),
                          fmaxf(acc[i][2][reg], acc[i][3][reg]));
          for (int d = 1; d < 16; d <<= 1) m = fmaxf(m, __shfl_xor(m, d));
          if (li == 0 && v < NV) ip += vwf[b * NV + v] * m;
        }
      }
    }
    float cm[4];
#pragma unroll
    for (int j = 0; j < 4; ++j) cm[j] = -3.0e38f;
#pragma unroll
    for (int i = 0; i < 4; ++i) {
      if (i < nt) {
#pragma unroll
      for (int reg = 0; reg < 4; ++reg) {
          int v = (tbase + i) * 16 + lg * 4 + reg;
          bool ok = v < NV;
#pragma unroll
          for (int j = 0; j < 4; ++j)
            cm[j] = fmaxf(cm[j], ok ? acc[i][j][reg] : -3.0e38f);
        }
      }
    }
#pragma unroll
    for (int j = 0; j < 4; ++j) {
      for (int d = 16; d < 64; d <<= 1) cm[j] = fmaxf(cm[j], __shfl_xor(cm[j], d));
      if (lg == 0) colv[w][j * 16 + li] = cm[j];
    }
  }
  for (int d = 1; d < 64; d <<= 1) ip += __shfl_xor(ip, d);
  if (lane == 0) redp[w] = ip;
  __syncthreads();
  if (tid < 128) {   // tid>>6==0 -> q0 (colv 0-3), ==1 -> q1 (colv 4-7)
    int qs = tid >> 6, t = tid & 63;
    int qe = 2 * qq + qs;
    float m = colv[qs * 4][t];
    if (diagblk) {
      int bi = coli[qs * 4][t];
#pragma unroll
      for (int w2 = 1; w2 < 4; ++w2) {
        float om = colv[qs * 4 + w2][t];
        int ov = coli[qs * 4 + w2][t];
        if (om > m || (om == m && ov < bi)) { m = om; bi = ov; }
      }
      if (b == qe) gMV[b * NT + t] = b * NV + bi;
    } else {
#pragma unroll
      for (int w2 = 1; w2 < 4; ++w2) m = fmaxf(m, colv[qs * 4 + w2][t]);
    }
    float p = twf[qe * NT + t] * m;
    for (int d = 1; d < 64; d <<= 1) p += __shfl_xor(p, d);
    if ((tid & 63) == 0) out[4096 + b * 64 + qe] = p;
  }
  if (tid == 0) {
    out[b * 64 + 2 * qq]     = redp[0] + redp[1] + redp[2] + redp[3];
    out[b * 64 + 2 * qq + 1] = redp[4] + redp[5] + redp[6] + redp[7];
  }
}

// ------- transpose-materialize (K-chunk-tiled dst [K/32][512][32]) + fused stats ----
__global__ void k_materialize(const short* __restrict__ ve_bf, const short* __restrict__ te_bf,
                              const int* __restrict__ gMT, const int* __restrict__ gMV,
                              const float* __restrict__ vwf, const float* __restrict__ twf,
                              short* __restrict__ tTw, short* __restrict__ mvT,
                              short* __restrict__ vTw, short* __restrict__ mtT,
                              float* __restrict__ statPart) {
  int z = blockIdx.z;
  int at = blockIdx.x, ct = blockIdx.y;
  int K = (z == 2 || z == 3) ? MROWS_V : MROWS_T;
  if (at * 64 >= K) return;
  const short* src; const int* g = 0; short* dst;
  bool applyW;
  const float* wS = (z <= 1) ? twf : vwf;
  if (z == 0)      { src = te_bf; dst = tTw; applyW = true;  }
  else if (z == 1) { src = ve_bf; g = gMV; dst = mvT; applyW = false; }
  else if (z == 2) { src = ve_bf; dst = vTw; applyW = true;  }
  else             { src = te_bf; g = gMT; dst = mtT; applyW = false; }
  __shared__ float tile[64][67];
  __shared__ float wrow[64];
  int tid = threadIdx.x;
  for (int u = tid; u < 512; u += 256) {
    int a = u >> 3, cseg = (u & 7) << 3;
    int ga = at * 64 + a;
    int row = g ? g[ga] : ga;
    bf16x8 vv = *(const bf16x8*)(src + (size_t)row * EDIM + ct * 64 + cseg);
#pragma unroll
    for (int j = 0; j < 8; j++) tile[a][cseg + j] = bf2f(vv[j]);
    if ((u & 7) == 0) wrow[a] = wS[ga];
  }
  __syncthreads();
  for (int u = tid; u < 512; u += 256) {
    int c = u >> 3, aseg = (u & 7) << 3;
    bf16x8 ov;
#pragma unroll
    for (int j = 0; j < 8; j++) {
      float x = tile[aseg + j][c];
      if (applyW) x *= wrow[aseg + j];
      ov[j] = (short)f2bf(x);
    }
    int kchunk = at * 2 + (aseg >> 5);   // K-chunk-tiled: [K/32][512][32]
    *(bf16x8*)(dst + ((size_t)kchunk * 512 + ct * 64 + c) * 32 + (aseg & 31)) = ov;
  }
  // ---- fused stats partials: 4 threads per column, 16 a's each
  int cl = tid >> 2, part = tid & 3;
  float s = 0, ssq = 0, sw = 0;
  for (int a = part * 16; a < part * 16 + 16; ++a) {
    float x = tile[a][cl];
    s += x; ssq += x * x; sw += wrow[a] * x;
  }
  for (int d = 1; d < 4; d <<= 1) {   // 4 consecutive lanes share a column
    s += __shfl_xor(s, d); ssq += __shfl_xor(ssq, d); sw += __shfl_xor(sw, d);
  }
  if (part == 0) {
    int cbase = (z == 0) ? 0 : (z == 1) ? 64 : (z == 2) ? 128 : 324;
    size_t sidx = ((size_t)(cbase + at) * 512 + ct * 64 + cl) * 3;
    statPart[sidx] = s; statPart[sidx + 1] = ssq; statPart[sidx + 2] = sw;
  }
}

// ------- MFMA weighted GEMM on K-chunk-tiled operands: 128x128 tile, 8 waves -------
// Balanced split-K: T planes z=0..3 (32 chunks each), V planes z=4..15
// (z-4<8: 33 chunks, else 32; total 392). z==16 = folded statfin plane.
__global__ __launch_bounds__(512, 2) void k_wgemm2(
    const short* __restrict__ tTw, const short* __restrict__ mvT,
    const short* __restrict__ vTw, const short* __restrict__ mtT,
    const float* __restrict__ statPart, float* __restrict__ stats,
    float* __restrict__ Spart) {
  int z = blockIdx.z;                 // 0..15 GEMM; 16 = statfin
  if (z == 16) {
    if (blockIdx.y != 0 || blockIdx.x >= 4) return;
    int m = blockIdx.x;               // 0..3
    int R = (m < 2) ? MROWS_T : MROWS_V;
    int nchunk = (m < 2) ? 64 : 196;
    int base = (m == 0) ? 0 : (m == 1) ? 64 : (m == 2) ? 128 : 324;
    int c = threadIdx.x;              // 512 threads = 512 cols
    float s = 0, ss = 0, sw = 0;
    for (int ch = 0; ch < nchunk; ch++) {
      size_t idx = ((size_t)(base + ch) * 512 + c) * 3;
      s += statPart[idx]; ss += statPart[idx + 1]; sw += statPart[idx + 2];
    }
    float mean = s / R;
    float var = (ss - s * mean) / (R - 1);  // ddof=1
    float rstd = 1.0f / sqrtf(var);
    stats[(m * 3 + 0) * 512 + c] = mean;
    stats[(m * 3 + 1) * 512 + c] = rstd;
    stats[(m * 3 + 2) * 512 + c] = sw;
    return;
  }
  __shared__ short As[2][128 * 32];
  __shared__ short Bs[2][128 * 32];
  int c0 = blockIdx.x * 128, d0 = blockIdx.y * 128;
  const short* A; const short* B; int nch; size_t a0c;
  if (z < 4) {                        // T-GEMM: 128 chunks over 4 slices
    A = tTw; B = mvT; nch = 32; a0c = (size_t)z * 32;
  } else {                            // V-GEMM: 392 chunks over 12 slices
    A = vTw; B = mtT;
    int vi = z - 4;
    if (vi < 8) { nch = 33; a0c = (size_t)vi * 33; }
    else        { nch = 32; a0c = 264 + (size_t)(vi - 8) * 32; }
  }
  int tid = threadIdx.x;
  int w = tid >> 6, lane = tid & 63, lg = lane >> 4, li = lane & 15;
  int fsw = (li + (li >> 2)) & 3;

  const short* aSrc; const short* bSrc;
  {
    int row = tid >> 2, seg = tid & 3;   // 512 units = 128 rows x 4 segs
    int ss = seg ^ swz4(row);
    aSrc = A + (a0c * 512 + (size_t)(c0 + row)) * 32 + ss * 8;
    bSrc = B + (a0c * 512 + (size_t)(d0 + row)) * 32 + ss * 8;
  }

  auto stage = [&](int bb) {           // 2 loads/wave
    gload16(aSrc, &As[bb][0] + (w * 64) * 8);
    aSrc += 512 * 32;
    gload16(bSrc, &Bs[bb][0] + (w * 64) * 8);
    bSrc += 512 * 32;
  };

  f32x4 acc[8];
#pragma unroll
  for (int j = 0; j < 8; ++j) acc[j] = (f32x4){0.f, 0.f, 0.f, 0.f};

  stage(0);
  int cur = 0;
  for (int ch = 0; ch < nch; ++ch) {
    __builtin_amdgcn_s_barrier();
    if (ch < nch - 1) {
      stage(cur ^ 1);
      asm volatile("s_waitcnt vmcnt(2)" ::: "memory");
    } else {
      asm volatile("s_waitcnt vmcnt(0)" ::: "memory");
    }
    __builtin_amdgcn_s_barrier();
    const short* Ab = &As[cur][0];
    const short* Bb = &Bs[cur][0];
    bf16x8 afr = *(const bf16x8*)(Ab + (w * 16 + li) * 32 + (lg ^ fsw) * 8);
    __builtin_amdgcn_s_setprio(1);
#pragma unroll
    for (int j = 0; j < 8; ++j) {
      bf16x8 bfr = *(const bf16x8*)(Bb + (j * 16 + li) * 32 + (lg ^ fsw) * 8);
      acc[j] = __builtin_amdgcn_mfma_f32_16x16x32_bf16(afr, bfr, acc[j], 0, 0, 0);
    }
    __builtin_amdgcn_s_setprio(0);
    cur ^= 1;
  }
  float* outp = Spart + (size_t)z * 512 * 512;
#pragma unroll
  for (int j = 0; j < 8; ++j) {
    int d = d0 + j * 16 + li;
#pragma unroll
    for (int reg = 0; reg < 4; ++reg)
      outp[(size_t)(c0 + w * 16 + lg * 4 + reg) * 512 + d] = acc[j][reg];
  }
}

// ---------------- assemble c = (c1+c2)/2 from closed form; loss partials ----------
// s1 = T-GEMM planes 0..3, s2 = V-GEMM planes 4..15.
__global__ void k_assemble(const float* __restrict__ Spart, const float* __restrict__ stats,
                           float* __restrict__ lossPart) {
  int c = blockIdx.x, tid = threadIdx.x;
  float muT = stats[0 * 512 + c], rsT = stats[1 * 512 + c], swT = stats[2 * 512 + c];
  float muV = stats[6 * 512 + c], rsV = stats[7 * 512 + c], swV = stats[8 * 512 + c];
  const float W = 64.0f, invB = 1.0f / 64.0f;
  float on = 0, off = 0;
  for (int d = tid; d < 512; d += 256) {
    float s1 = 0, s2 = 0;
#pragma unroll
    for (int sl = 0; sl < 4; sl++)
      s1 += Spart[((size_t)sl * 512 + c) * 512 + d];
#pragma unroll
    for (int sl = 4; sl < 16; sl++)
      s2 += Spart[((size_t)sl * 512 + c) * 512 + d];
    float muMV = stats[3 * 512 + d], rsMV = stats[4 * 512 + d], swMV = stats[5 * 512 + d];
    float muMT = stats[9 * 512 + d], rsMT = stats[10 * 512 + d], swMT = stats[11 * 512 + d];
    float c1 = (s1 - muT * swMV - muMV * swT + muT * muMV * W) * rsT * rsMV * invB;
    float c2 = (s2 - muV * swMT - muMT * swV + muV * muMT * W) * rsV * rsMT * invB;
    float cc = 0.5f * (c1 + c2);
    if (d == c) { float dd = cc - 1.0f; on += dd * dd; }
    else off += cc * cc;
  }
  __shared__ float r1[4], r2[4];
  for (int s = 1; s < 64; s <<= 1) { on += __shfl_xor(on, s); off += __shfl_xor(off, s); }
  if ((tid & 63) == 0) { r1[tid >> 6] = on; r2[tid >> 6] = off; }
  __syncthreads();
  if (tid == 0) {
    lossPart[c * 2] = r1[0] + r1[1] + r1[2] + r1[3];
    lossPart[c * 2 + 1] = r2[0] + r2[1] + r2[2] + r2[3];
  }
}

__global__ void k_loss(const float* __restrict__ lossPart, float* __restrict__ out) {
  int tid = threadIdx.x;
  float on = 0, off = 0;
  for (int i = tid; i < 512; i += 256) { on += lossPart[2 * i]; off += lossPart[2 * i + 1]; }
  __shared__ float r1[4], r2[4];
  for (int s = 1; s < 64; s <<= 1) { on += __shfl_xor(on, s); off += __shfl_xor(off, s); }
  if ((tid & 63) == 0) { r1[tid >> 6] = on; r2[tid >> 6] = off; }
  __syncthreads();
  if (tid == 0)
    out[8192] = 0.1f * ((r1[0] + r1[1] + r1[2] + r1[3]) +
                        0.06f * (r2[0] + r2[1] + r2[2] + r2[3]));
}

extern "C" void kernel_launch(void* const* d_in, const int* in_sizes, int n_in,
                              void* d_out, int out_size, void* d_ws, size_t ws_size,
                              hipStream_t stream) {
  (void)in_sizes; (void)n_in; (void)out_size; (void)ws_size;
  const float* v_tok  = (const float*)d_in[1];
  const float* t_tok  = (const float*)d_in[3];
  const float* Wv_tok = (const float*)d_in[8];
  const float* Wt_tok = (const float*)d_in[10];
  const float* bv_tok = (const float*)d_in[9];
  const float* bt_tok = (const float*)d_in[11];
  const float* wv_fc  = (const float*)d_in[12];
  const float* bv_fc  = (const float*)d_in[13];
  const float* wt_fc  = (const float*)d_in[14];
  const float* bt_fc  = (const float*)d_in[15];
  const int*   tlen   = (const int*)d_in[16];
  float* out = (float*)d_out;

  char* wsb = (char*)d_ws;
  short* v_tok_bf = (short*)wsb;                       // 9,633,792 sh
  short* t_tok_bf = v_tok_bf + (size_t)9633792;        // 3,145,728 sh
  short* WvT      = t_tok_bf + (size_t)3145728;        //   393,216 sh
  short* WtT      = WvT + (size_t)393216;              //   393,216 sh
  short* tTw = (short*)wsb;                            // 512*4096 (alias, phase2)
  short* mvT = tTw + (size_t)2097152;                  // 512*4096
  short* vTw = mvT + (size_t)2097152;                  // 512*12544
  short* ve_bf = (short*)(wsb + 27131904);             // 6,422,528 sh
  short* te_bf = ve_bf + (size_t)6422528;              // 2,097,152 sh
  float* Spart = (float*)(wsb + 27131904);             // 16*512*512 f (alias, phase-b)
  short* mtT = (short*)(wsb + 44171264);               // 512*12544
  float* vwf = (float*)(wsb + 57016320);               // 12544
  float* twf = vwf + 12544;                            // 4096
  int* gMT = (int*)(twf + 4096);                       // 12544
  int* gMV = gMT + 12544;                              // 4096
  float* statPart = (float*)(gMV + 4096);              // 520*512*3 f (3.2 MB)
  float* stats = statPart + (size_t)520 * 512 * 3;     // 12*512
  float* lossPart = stats + 6144;                      // 1024

  k_prep<<<7008, 256, 0, stream>>>(v_tok, v_tok_bf, 1204224, t_tok, t_tok_bf, 393216,
                                   Wv_tok, Wt_tok, WvT, WtT);
  k_proj_mfma2<<<dim3(4, 130), 256, 0, stream>>>(v_tok_bf, t_tok_bf, WvT, WtT,
                                                 bv_tok, bt_tok, ve_bf, te_bf);
  k_normfc2<<<4160, 256, 0, stream>>>(ve_bf, te_bf, wv_fc, wt_fc, bv_fc, bt_fc, vwf, twf);
  k_softmax<<<128, 256, 0, stream>>>(vwf, twf, tlen);
  k_sim<<<2048, 512, 0, stream>>>(ve_bf, te_bf, vwf, twf, out, gMT, gMV);
  k_materialize<<<dim3(196, 8, 4), 256, 0, stream>>>(ve_bf, te_bf, gMT, gMV, vwf, twf,
                                                     tTw, mvT, vTw, mtT, statPart);
  k_wgemm2<<<dim3(4, 4, 17), 512, 0, stream>>>(tTw, mvT, vTw, mtT, statPart, stats, Spart);
  k_assemble<<<512, 256, 0, stream>>>(Spart, stats, lossPart);
  k_loss<<<1, 256, 0, stream>>>(lossPart, out);
}